// Round 2
// baseline (3332.810 us; speedup 1.0000x reference)
//
#include <hip/hip_runtime.h>
#include <hip/hip_bf16.h>
#include <math.h>

#define BB 2
#define SS 2048
#define EE 1024
#define HH 16
#define DD 64
#define NROW (BB*SS)
#define SCALE 0.125f

__device__ __forceinline__ float dot4(float4 a, float4 b){
  return a.x*b.x + a.y*b.y + a.z*b.z + a.w*b.w;
}

// ---------------------------------------------------------------------------
// GEMM: out[n,j] = sum_i X[n,i] * W[j,i] + bias[j]   (X @ W.T + b)
// X: [4096,1024] row-major, W: [1024,1024] row-major, out: [4096,1024].
// 128x128 tile, BK=32, 256 threads, 8x8 per-thread micro-tile.
// LDS layout: s[k][chunk-swizzled m], chunk' = (m>>2) ^ (k&31).
// ---------------------------------------------------------------------------
__device__ __forceinline__ void gemm_body(const float* __restrict__ X,
                                          const float* __restrict__ W,
                                          const float* __restrict__ bias,
                                          float* __restrict__ out)
{
  __shared__ float sA[32][128];
  __shared__ float sB[32][128];
  const int tid = threadIdx.x;
  const int tm = tid >> 4;     // 0..15
  const int tn = tid & 15;     // 0..15
  const int m0 = blockIdx.y * 128;
  const int n0 = blockIdx.x * 128;

  float acc[8][8];
#pragma unroll
  for (int i = 0; i < 8; ++i)
#pragma unroll
    for (int j = 0; j < 8; ++j) acc[i][j] = 0.f;

  for (int kt = 0; kt < EE; kt += 32) {
    __syncthreads();
#pragma unroll
    for (int s = 0; s < 4; ++s) {
      int slot = tid + s * 256;      // 0..1023
      int row  = slot >> 3;          // 0..127
      int c4   = slot & 7;           // 0..7
      float4 av = *(const float4*)&X[(size_t)(m0 + row) * EE + kt + c4 * 4];
      float4 bv = *(const float4*)&W[(size_t)(n0 + row) * EE + kt + c4 * 4];
#pragma unroll
      for (int j = 0; j < 4; ++j) {
        int k  = c4 * 4 + j;
        int ch = (row >> 2) ^ (k & 31);
        sA[k][ch * 4 + (row & 3)] = ((const float*)&av)[j];
        sB[k][ch * 4 + (row & 3)] = ((const float*)&bv)[j];
      }
    }
    __syncthreads();
#pragma unroll
    for (int k = 0; k < 32; ++k) {
      const int sw = k & 31;
      float4 a0 = *(const float4*)&sA[k][((tm        ^ sw)) * 4];
      float4 a1 = *(const float4*)&sA[k][(((16 + tm) ^ sw)) * 4];
      float4 b0 = *(const float4*)&sB[k][((tn        ^ sw)) * 4];
      float4 b1 = *(const float4*)&sB[k][(((16 + tn) ^ sw)) * 4];
      float a[8]  = {a0.x, a0.y, a0.z, a0.w, a1.x, a1.y, a1.z, a1.w};
      float bb[8] = {b0.x, b0.y, b0.z, b0.w, b1.x, b1.y, b1.z, b1.w};
#pragma unroll
      for (int i = 0; i < 8; ++i)
#pragma unroll
        for (int j = 0; j < 8; ++j)
          acc[i][j] = fmaf(a[i], bb[j], acc[i][j]);
    }
  }

  float4 bi0 = *(const float4*)&bias[n0 + tn * 4];
  float4 bi1 = *(const float4*)&bias[n0 + 64 + tn * 4];
#pragma unroll
  for (int i = 0; i < 8; ++i) {
    int m = m0 + ((i < 4) ? (tm * 4 + i) : (64 + tm * 4 + (i - 4)));
    float4 o0 = {acc[i][0] + bi0.x, acc[i][1] + bi0.y,
                 acc[i][2] + bi0.z, acc[i][3] + bi0.w};
    float4 o1 = {acc[i][4] + bi1.x, acc[i][5] + bi1.y,
                 acc[i][6] + bi1.z, acc[i][7] + bi1.w};
    *(float4*)&out[(size_t)m * EE + n0 + tn * 4]      = o0;
    *(float4*)&out[(size_t)m * EE + n0 + 64 + tn * 4] = o1;
  }
}

__global__ __launch_bounds__(256) void k_gemm_qkv(
    const float* __restrict__ xq, const float* __restrict__ xk,
    const float* __restrict__ xv,
    const float* __restrict__ Wq, const float* __restrict__ Wk,
    const float* __restrict__ Wv,
    const float* __restrict__ bq, const float* __restrict__ bk,
    const float* __restrict__ bv,
    float* __restrict__ Q, float* __restrict__ K, float* __restrict__ V)
{
  const int z = blockIdx.z;
  const float* X = (z == 0) ? xq : (z == 1) ? xk : xv;
  const float* W = (z == 0) ? Wq : (z == 1) ? Wk : Wv;
  const float* b = (z == 0) ? bq : (z == 1) ? bk : bv;
  float*       O = (z == 0) ? Q  : (z == 1) ? K  : V;
  gemm_body(X, W, b, O);
}

__global__ __launch_bounds__(256) void k_gemm_o(
    const float* __restrict__ att, const float* __restrict__ Wo,
    const float* __restrict__ bo, float* __restrict__ out)
{
  gemm_body(att, Wo, bo, out);
}

// ---------------------------------------------------------------------------
// Attention: block = (b, 16 q-rows). Loops over 16 heads.
//   pass 1: row max m / sumexp l  (online, shfl-xor merged across 32 lanes)
//   pass 2: p = exp(s-m)/l  -> avg_attn global RMW, PV accumulate (k-split 2)
// LDS: Qs[16][64] (scaled), Ks[128][64] swz, Vs[128][64] swz, pS[16][128].
// ---------------------------------------------------------------------------
__global__ __launch_bounds__(256) void k_attn(
    const float* __restrict__ Qg, const float* __restrict__ Kg,
    const float* __restrict__ Vg,
    float* __restrict__ att, float* __restrict__ avg)
{
  __shared__ float Qs[16][64];
  __shared__ float Ks[128][64];
  __shared__ float Vs[128][64];
  __shared__ float pS[16][128];

  const int tid = threadIdx.x;
  const int b   = blockIdx.y;
  const int q0  = blockIdx.x * 16;
  const int tq  = tid >> 5;       // 0..7  -> q rows 2tq, 2tq+1
  const int t32 = tid & 31;       // pass1/s: k quad; PV: (td4, ks)
  const int td4 = t32 >> 1;       // 0..15 -> d = td4*4..+3
  const int ks  = t32 & 1;        // PV k-split half

  const float* Qb = Qg + (size_t)b * SS * EE;
  const float* Kb = Kg + (size_t)b * SS * EE;
  const float* Vb = Vg + (size_t)b * SS * EE;

  for (int h = 0; h < HH; ++h) {
    // stage Q head slice (scaled by SCALE so s is pre-scaled)
    {
      int r = tid >> 4, c4 = tid & 15;
      float4 v = *(const float4*)&Qb[(size_t)(q0 + r) * EE + h * 64 + c4 * 4];
      v.x *= SCALE; v.y *= SCALE; v.z *= SCALE; v.w *= SCALE;
      *(float4*)&Qs[r][c4 * 4] = v;
    }

    // ---------------- pass 1: m, l ----------------
    float m[2] = {-1e30f, -1e30f};
    float l[2] = {0.f, 0.f};
    for (int kt = 0; kt < SS; kt += 128) {
      __syncthreads();
#pragma unroll
      for (int i = 0; i < 8; ++i) {
        int slot = tid + i * 256;
        int r = slot >> 4, c4 = slot & 15;
        float4 v = *(const float4*)&Kb[(size_t)(kt + r) * EE + h * 64 + c4 * 4];
        *(float4*)&Ks[r][((c4 ^ ((r >> 2) & 15))) * 4] = v;
      }
      __syncthreads();
      float s[2][4] = {{0, 0, 0, 0}, {0, 0, 0, 0}};
#pragma unroll
      for (int c = 0; c < 16; ++c) {
        float4 qf0 = *(const float4*)&Qs[2 * tq][c * 4];
        float4 qf1 = *(const float4*)&Qs[2 * tq + 1][c * 4];
#pragma unroll
        for (int j = 0; j < 4; ++j) {
          float4 kf = *(const float4*)&Ks[t32 * 4 + j][((c ^ (t32 & 15))) * 4];
          s[0][j] += dot4(qf0, kf);
          s[1][j] += dot4(qf1, kf);
        }
      }
#pragma unroll
      for (int r2 = 0; r2 < 2; ++r2) {
        float mx = fmaxf(fmaxf(s[r2][0], s[r2][1]), fmaxf(s[r2][2], s[r2][3]));
        float mn = fmaxf(m[r2], mx);
        l[r2] = l[r2] * __expf(m[r2] - mn)
              + __expf(s[r2][0] - mn) + __expf(s[r2][1] - mn)
              + __expf(s[r2][2] - mn) + __expf(s[r2][3] - mn);
        m[r2] = mn;
      }
    }
    // merge across the 32 lanes sharing this q-pair
#pragma unroll
    for (int off = 16; off >= 1; off >>= 1) {
#pragma unroll
      for (int r2 = 0; r2 < 2; ++r2) {
        float mo = __shfl_xor(m[r2], off);
        float lo = __shfl_xor(l[r2], off);
        float mn = fmaxf(m[r2], mo);
        l[r2] = l[r2] * __expf(m[r2] - mn) + lo * __expf(mo - mn);
        m[r2] = mn;
      }
    }
    const float inv0 = 1.f / l[0];
    const float inv1 = 1.f / l[1];

    // ---------------- pass 2: p, avg, PV ----------------
    float acc[2][4] = {{0, 0, 0, 0}, {0, 0, 0, 0}};
    for (int kt = 0; kt < SS; kt += 128) {
      __syncthreads();
#pragma unroll
      for (int i = 0; i < 8; ++i) {
        int slot = tid + i * 256;
        int r = slot >> 4, c4 = slot & 15;
        float4 kv = *(const float4*)&Kb[(size_t)(kt + r) * EE + h * 64 + c4 * 4];
        float4 vv = *(const float4*)&Vb[(size_t)(kt + r) * EE + h * 64 + c4 * 4];
        *(float4*)&Ks[r][((c4 ^ ((r >> 2) & 15))) * 4] = kv;
        *(float4*)&Vs[r][((c4 ^ ((r >> 4) & 15))) * 4] = vv;
      }
      __syncthreads();
      {
        float s[2][4] = {{0, 0, 0, 0}, {0, 0, 0, 0}};
#pragma unroll
        for (int c = 0; c < 16; ++c) {
          float4 qf0 = *(const float4*)&Qs[2 * tq][c * 4];
          float4 qf1 = *(const float4*)&Qs[2 * tq + 1][c * 4];
#pragma unroll
          for (int j = 0; j < 4; ++j) {
            float4 kf = *(const float4*)&Ks[t32 * 4 + j][((c ^ (t32 & 15))) * 4];
            s[0][j] += dot4(qf0, kf);
            s[1][j] += dot4(qf1, kf);
          }
        }
        float4 p0, p1;
        p0.x = __expf(s[0][0] - m[0]) * inv0;
        p0.y = __expf(s[0][1] - m[0]) * inv0;
        p0.z = __expf(s[0][2] - m[0]) * inv0;
        p0.w = __expf(s[0][3] - m[0]) * inv0;
        p1.x = __expf(s[1][0] - m[1]) * inv1;
        p1.y = __expf(s[1][1] - m[1]) * inv1;
        p1.z = __expf(s[1][2] - m[1]) * inv1;
        p1.w = __expf(s[1][3] - m[1]) * inv1;
        *(float4*)&pS[2 * tq][t32 * 4]     = p0;
        *(float4*)&pS[2 * tq + 1][t32 * 4] = p1;
      }
      __syncthreads();
      // avg_attn RMW (h==0 overwrites poison)
#pragma unroll
      for (int i = 0; i < 2; ++i) {
        int slot = tid + i * 256;
        int row  = slot >> 5;     // 0..15
        int c4k  = slot & 31;     // 0..31
        float4 p = *(const float4*)&pS[row][c4k * 4];
        const float ih = 1.f / HH;
        p.x *= ih; p.y *= ih; p.z *= ih; p.w *= ih;
        float* gp = avg + (size_t)(b * SS + q0 + row) * SS + kt + c4k * 4;
        if (h) {
          float4 old = *(const float4*)gp;
          p.x += old.x; p.y += old.y; p.z += old.z; p.w += old.w;
        }
        *(float4*)gp = p;
      }
      // PV: rows 2tq,2tq+1 x d td4*4..+3, k-half ks
#pragma unroll
      for (int kk = 0; kk < 64; kk += 4) {
        int kb = ks * 64 + kk;
        float4 p0 = *(const float4*)&pS[2 * tq][kb];
        float4 p1 = *(const float4*)&pS[2 * tq + 1][kb];
        const float p0a[4] = {p0.x, p0.y, p0.z, p0.w};
        const float p1a[4] = {p1.x, p1.y, p1.z, p1.w};
#pragma unroll
        for (int j = 0; j < 4; ++j) {
          int kr = kb + j;
          float4 vf = *(const float4*)&Vs[kr][((td4 ^ ((kr >> 4) & 15))) * 4];
          acc[0][0] = fmaf(p0a[j], vf.x, acc[0][0]);
          acc[0][1] = fmaf(p0a[j], vf.y, acc[0][1]);
          acc[0][2] = fmaf(p0a[j], vf.z, acc[0][2]);
          acc[0][3] = fmaf(p0a[j], vf.w, acc[0][3]);
          acc[1][0] = fmaf(p1a[j], vf.x, acc[1][0]);
          acc[1][1] = fmaf(p1a[j], vf.y, acc[1][1]);
          acc[1][2] = fmaf(p1a[j], vf.z, acc[1][2]);
          acc[1][3] = fmaf(p1a[j], vf.w, acc[1][3]);
        }
      }
    }
    // combine the two k-split halves via LDS scratch (reuse pS), store att
    __syncthreads();
    {
      float* sc = &pS[0][0];
      int base = (tq * 16 + td4) * 8;
      if (ks == 1) {
        *(float4*)&sc[base]     = *(float4*)&acc[0][0];
        *(float4*)&sc[base + 4] = *(float4*)&acc[1][0];
      }
    }
    __syncthreads();
    if (ks == 0) {
      float* sc = &pS[0][0];
      int base = (tq * 16 + td4) * 8;
      float4 o0 = *(const float4*)&sc[base];
      float4 o1 = *(const float4*)&sc[base + 4];
      o0.x += acc[0][0]; o0.y += acc[0][1]; o0.z += acc[0][2]; o0.w += acc[0][3];
      o1.x += acc[1][0]; o1.y += acc[1][1]; o1.z += acc[1][2]; o1.w += acc[1][3];
      *(float4*)&att[(size_t)(b * SS + q0 + 2 * tq) * EE + h * 64 + td4 * 4]     = o0;
      *(float4*)&att[(size_t)(b * SS + q0 + 2 * tq + 1) * EE + h * 64 + td4 * 4] = o1;
    }
    __syncthreads();
  }
}

// ---------------------------------------------------------------------------
extern "C" void kernel_launch(void* const* d_in, const int* in_sizes, int n_in,
                              void* d_out, int out_size, void* d_ws, size_t ws_size,
                              hipStream_t stream) {
  const float* q  = (const float*)d_in[0];
  const float* k  = (const float*)d_in[1];
  const float* v  = (const float*)d_in[2];
  const float* Wq = (const float*)d_in[3];
  const float* bq = (const float*)d_in[4];
  const float* Wk = (const float*)d_in[5];
  const float* bk = (const float*)d_in[6];
  const float* Wv = (const float*)d_in[7];
  const float* bv = (const float*)d_in[8];
  const float* Wo = (const float*)d_in[9];
  const float* bo = (const float*)d_in[10];

  float* ws  = (float*)d_ws;
  float* Q   = ws;                 // [4096,1024]
  float* K   = ws + 4194304;       // [4096,1024]
  float* V   = ws + 8388608;       // [4096,1024]
  float* att = ws + 12582912;      // [4096,1024]

  float* outp = (float*)d_out;           // output [B,S,E]
  float* avg  = outp + 4194304;          // avg_attn [B,S,S]

  dim3 gqkv(EE / 128, NROW / 128, 3);    // (8,32,3)
  k_gemm_qkv<<<gqkv, 256, 0, stream>>>(q, k, v, Wq, Wk, Wv, bq, bk, bv, Q, K, V);

  dim3 gattn(SS / 16, BB);               // (128,2)
  k_attn<<<gattn, 256, 0, stream>>>(Q, K, V, att, avg);

  dim3 go(EE / 128, NROW / 128);         // (8,32)
  k_gemm_o<<<go, 256, 0, stream>>>(att, Wo, bo, outp);
}

// Round 6
// 2028.722 us; speedup vs baseline: 1.6428x; 1.6428x over previous
//
#include <hip/hip_runtime.h>
#include <hip/hip_bf16.h>
#include <math.h>

#define BB 2
#define SS 2048
#define EE 1024
#define HH 16
#define DD 64
#define NROW (BB*SS)
#define SCALE 0.125f

__device__ __forceinline__ float dot4(float4 a, float4 b){
  return a.x*b.x + a.y*b.y + a.z*b.z + a.w*b.w;
}

// ---------------------------------------------------------------------------
// GEMM: out = X @ W.T + b  (unchanged from R2 baseline; proven correct)
// ---------------------------------------------------------------------------
__device__ __forceinline__ void gemm_body(const float* __restrict__ X,
                                          const float* __restrict__ W,
                                          const float* __restrict__ bias,
                                          float* __restrict__ out)
{
  __shared__ float sA[32][128];
  __shared__ float sB[32][128];
  const int tid = threadIdx.x;
  const int tm = tid >> 4;
  const int tn = tid & 15;
  const int m0 = blockIdx.y * 128;
  const int n0 = blockIdx.x * 128;

  float acc[8][8];
#pragma unroll
  for (int i = 0; i < 8; ++i)
#pragma unroll
    for (int j = 0; j < 8; ++j) acc[i][j] = 0.f;

  for (int kt = 0; kt < EE; kt += 32) {
    __syncthreads();
#pragma unroll
    for (int s = 0; s < 4; ++s) {
      int slot = tid + s * 256;
      int row  = slot >> 3;
      int c4   = slot & 7;
      float4 av = *(const float4*)&X[(size_t)(m0 + row) * EE + kt + c4 * 4];
      float4 bv = *(const float4*)&W[(size_t)(n0 + row) * EE + kt + c4 * 4];
#pragma unroll
      for (int j = 0; j < 4; ++j) {
        int k  = c4 * 4 + j;
        int ch = (row >> 2) ^ (k & 31);
        sA[k][ch * 4 + (row & 3)] = ((const float*)&av)[j];
        sB[k][ch * 4 + (row & 3)] = ((const float*)&bv)[j];
      }
    }
    __syncthreads();
#pragma unroll
    for (int k = 0; k < 32; ++k) {
      const int sw = k & 31;
      float4 a0 = *(const float4*)&sA[k][((tm        ^ sw)) * 4];
      float4 a1 = *(const float4*)&sA[k][(((16 + tm) ^ sw)) * 4];
      float4 b0 = *(const float4*)&sB[k][((tn        ^ sw)) * 4];
      float4 b1 = *(const float4*)&sB[k][(((16 + tn) ^ sw)) * 4];
      float a[8]  = {a0.x, a0.y, a0.z, a0.w, a1.x, a1.y, a1.z, a1.w};
      float bb[8] = {b0.x, b0.y, b0.z, b0.w, b1.x, b1.y, b1.z, b1.w};
#pragma unroll
      for (int i = 0; i < 8; ++i)
#pragma unroll
        for (int j = 0; j < 8; ++j)
          acc[i][j] = fmaf(a[i], bb[j], acc[i][j]);
    }
  }

  float4 bi0 = *(const float4*)&bias[n0 + tn * 4];
  float4 bi1 = *(const float4*)&bias[n0 + 64 + tn * 4];
#pragma unroll
  for (int i = 0; i < 8; ++i) {
    int m = m0 + ((i < 4) ? (tm * 4 + i) : (64 + tm * 4 + (i - 4)));
    float4 o0 = {acc[i][0] + bi0.x, acc[i][1] + bi0.y,
                 acc[i][2] + bi0.z, acc[i][3] + bi0.w};
    float4 o1 = {acc[i][4] + bi1.x, acc[i][5] + bi1.y,
                 acc[i][6] + bi1.z, acc[i][7] + bi1.w};
    *(float4*)&out[(size_t)m * EE + n0 + tn * 4]      = o0;
    *(float4*)&out[(size_t)m * EE + n0 + 64 + tn * 4] = o1;
  }
}

__global__ __launch_bounds__(256) void k_gemm_qkv(
    const float* __restrict__ xq, const float* __restrict__ xk,
    const float* __restrict__ xv,
    const float* __restrict__ Wq, const float* __restrict__ Wk,
    const float* __restrict__ Wv,
    const float* __restrict__ bq, const float* __restrict__ bk,
    const float* __restrict__ bv,
    float* __restrict__ Q, float* __restrict__ K, float* __restrict__ V)
{
  const int z = blockIdx.z;
  const float* X = (z == 0) ? xq : (z == 1) ? xk : xv;
  const float* W = (z == 0) ? Wq : (z == 1) ? Wk : Wv;
  const float* b = (z == 0) ? bq : (z == 1) ? bk : bv;
  float*       O = (z == 0) ? Q  : (z == 1) ? K  : V;
  gemm_body(X, W, b, O);
}

__global__ __launch_bounds__(256) void k_gemm_o(
    const float* __restrict__ att, const float* __restrict__ Wo,
    const float* __restrict__ bo, float* __restrict__ out)
{
  gemm_body(att, Wo, bo, out);
}

// Swizzle for [*][64] fp32 tiles read row-distinct: chunk' = c ^ (r & 15)
#define SWZ(r, c) (((c) ^ ((r) & 15)) * 4)

// ---------------------------------------------------------------------------
// k_flash: flash attention, one (b, h, 64-row q-tile) per block, 256 thr.
// Online softmax; writes att[b,q,h*64+d] and mln[b,h,q] = m + ln(l).
// Micro-tile 4q x 4k (s) and 4q x 4d (PV acc) per thread; ty=tid>>4, tx=tid&15.
// LDS 64 KB -> 2 blocks/CU, 8 waves/CU.
// ---------------------------------------------------------------------------
__global__ __launch_bounds__(256) void k_flash(
    const float* __restrict__ Qg, const float* __restrict__ Kg,
    const float* __restrict__ Vg,
    float* __restrict__ att, float* __restrict__ mln)
{
  __shared__ float Qs[64][64];
  __shared__ float Ks[64][64];
  __shared__ float Vs[64][64];
  __shared__ float pS[64][64];

  const int tid = threadIdx.x;
  const int ty  = tid >> 4;   // 0..15 -> q rows ty*4..+3
  const int tx  = tid & 15;   // 0..15 -> k cols / d cols tx*4..+3
  const int q0  = blockIdx.x * 64;
  const int h   = blockIdx.y;
  const int b   = blockIdx.z;

  const float* Qb = Qg + (size_t)b * SS * EE + h * 64;
  const float* Kb = Kg + (size_t)b * SS * EE + h * 64;
  const float* Vb = Vg + (size_t)b * SS * EE + h * 64;

  // stage Q tile (scaled)
  {
    int r  = tid >> 2;          // 0..63
    int c4 = tid & 3;
#pragma unroll
    for (int u = 0; u < 4; ++u) {
      int c = u * 4 + c4;       // 0..15
      float4 v = *(const float4*)&Qb[(size_t)(q0 + r) * EE + c * 4];
      v.x *= SCALE; v.y *= SCALE; v.z *= SCALE; v.w *= SCALE;
      *(float4*)&Qs[r][SWZ(r, c)] = v;
    }
  }

  float m[4] = {-1e30f, -1e30f, -1e30f, -1e30f};
  float l[4] = {0.f, 0.f, 0.f, 0.f};
  float acc[4][4];
#pragma unroll
  for (int i = 0; i < 4; ++i)
#pragma unroll
    for (int j = 0; j < 4; ++j) acc[i][j] = 0.f;

  for (int kt = 0; kt < SS; kt += 64) {
    __syncthreads();   // protect Ks/Vs/pS from previous iteration's readers
    {
      int r  = tid >> 2;
      int c4 = tid & 3;
#pragma unroll
      for (int u = 0; u < 4; ++u) {
        int c = u * 4 + c4;
        float4 kv = *(const float4*)&Kb[(size_t)(kt + r) * EE + c * 4];
        float4 vv = *(const float4*)&Vb[(size_t)(kt + r) * EE + c * 4];
        *(float4*)&Ks[r][SWZ(r, c)] = kv;
        *(float4*)&Vs[r][SWZ(r, c)] = vv;
      }
    }
    __syncthreads();

    // s-tile: 4q x 4k per thread
    float s[4][4] = {{0,0,0,0},{0,0,0,0},{0,0,0,0},{0,0,0,0}};
#pragma unroll
    for (int c = 0; c < 16; ++c) {
      float4 qf[4], kf[4];
#pragma unroll
      for (int i = 0; i < 4; ++i) {
        int r = ty * 4 + i;
        qf[i] = *(const float4*)&Qs[r][SWZ(r, c)];
      }
#pragma unroll
      for (int j = 0; j < 4; ++j) {
        int r = tx * 4 + j;
        kf[j] = *(const float4*)&Ks[r][SWZ(r, c)];
      }
#pragma unroll
      for (int i = 0; i < 4; ++i)
#pragma unroll
        for (int j = 0; j < 4; ++j)
          s[i][j] += dot4(qf[i], kf[j]);
    }

    // online softmax update per q-row (reduce over the 16 tx lanes)
#pragma unroll
    for (int i = 0; i < 4; ++i) {
      float tmax = fmaxf(fmaxf(s[i][0], s[i][1]), fmaxf(s[i][2], s[i][3]));
#pragma unroll
      for (int off = 8; off >= 1; off >>= 1)
        tmax = fmaxf(tmax, __shfl_xor(tmax, off));
      float mn = fmaxf(m[i], tmax);
      float sc = __expf(m[i] - mn);
      float p0 = __expf(s[i][0] - mn);
      float p1 = __expf(s[i][1] - mn);
      float p2 = __expf(s[i][2] - mn);
      float p3 = __expf(s[i][3] - mn);
      s[i][0] = p0; s[i][1] = p1; s[i][2] = p2; s[i][3] = p3;
      float tsum = p0 + p1 + p2 + p3;
#pragma unroll
      for (int off = 8; off >= 1; off >>= 1)
        tsum += __shfl_xor(tsum, off);
      l[i] = l[i] * sc + tsum;
      m[i] = mn;
      acc[i][0] *= sc; acc[i][1] *= sc; acc[i][2] *= sc; acc[i][3] *= sc;
      int r = ty * 4 + i;
      *(float4*)&pS[r][SWZ(r, tx)] = *(float4*)&s[i][0];
    }
    __syncthreads();

    // PV: acc[4q][4d] += pS[64q][64k-tile] @ Vs[64k][4d]
#pragma unroll
    for (int kk = 0; kk < 16; ++kk) {
      float4 pf[4], vf[4];
#pragma unroll
      for (int i = 0; i < 4; ++i) {
        int r = ty * 4 + i;
        pf[i] = *(const float4*)&pS[r][SWZ(r, kk)];
      }
#pragma unroll
      for (int kc = 0; kc < 4; ++kc) {
        int r = kk * 4 + kc;
        vf[kc] = *(const float4*)&Vs[r][SWZ(r, tx)];
      }
#pragma unroll
      for (int i = 0; i < 4; ++i) {
        const float pa[4] = {pf[i].x, pf[i].y, pf[i].z, pf[i].w};
#pragma unroll
        for (int kc = 0; kc < 4; ++kc) {
          acc[i][0] = fmaf(pa[kc], vf[kc].x, acc[i][0]);
          acc[i][1] = fmaf(pa[kc], vf[kc].y, acc[i][1]);
          acc[i][2] = fmaf(pa[kc], vf[kc].z, acc[i][2]);
          acc[i][3] = fmaf(pa[kc], vf[kc].w, acc[i][3]);
        }
      }
    }
  }

  // epilogue
#pragma unroll
  for (int i = 0; i < 4; ++i) {
    int q = q0 + ty * 4 + i;
    float inv = 1.f / l[i];
    float4 o = {acc[i][0] * inv, acc[i][1] * inv, acc[i][2] * inv, acc[i][3] * inv};
    *(float4*)&att[(size_t)(b * SS + q) * EE + h * 64 + tx * 4] = o;
    if (tx == 0)
      mln[((size_t)(b * HH + h)) * SS + q] = m[i] + __logf(l[i]);
  }
}

// ---------------------------------------------------------------------------
// k_avg: one block per (b, 64q x 64k tile); loops 16 heads, recomputes scores,
// p = exp(s - mln), accumulates avg in registers, single write (no RMW/race).
// LDS 32 KB -> 5 blocks/CU, 20 waves/CU.
// ---------------------------------------------------------------------------
__global__ __launch_bounds__(256) void k_avg(
    const float* __restrict__ Qg, const float* __restrict__ Kg,
    const float* __restrict__ mln, float* __restrict__ avg)
{
  __shared__ float Qs[64][64];
  __shared__ float Ks[64][64];

  const int tid = threadIdx.x;
  const int ty  = tid >> 4;
  const int tx  = tid & 15;
  const int k0  = blockIdx.x * 64;
  const int q0  = blockIdx.y * 64;
  const int b   = blockIdx.z;

  float av[4][4];
#pragma unroll
  for (int i = 0; i < 4; ++i)
#pragma unroll
    for (int j = 0; j < 4; ++j) av[i][j] = 0.f;

  for (int h = 0; h < HH; ++h) {
    const float* Qb = Qg + (size_t)b * SS * EE + h * 64;
    const float* Kb = Kg + (size_t)b * SS * EE + h * 64;
    __syncthreads();
    {
      int r  = tid >> 2;
      int c4 = tid & 3;
#pragma unroll
      for (int u = 0; u < 4; ++u) {
        int c = u * 4 + c4;
        float4 qv = *(const float4*)&Qb[(size_t)(q0 + r) * EE + c * 4];
        qv.x *= SCALE; qv.y *= SCALE; qv.z *= SCALE; qv.w *= SCALE;
        float4 kv = *(const float4*)&Kb[(size_t)(k0 + r) * EE + c * 4];
        *(float4*)&Qs[r][SWZ(r, c)] = qv;
        *(float4*)&Ks[r][SWZ(r, c)] = kv;
      }
    }
    __syncthreads();

    float s[4][4] = {{0,0,0,0},{0,0,0,0},{0,0,0,0},{0,0,0,0}};
#pragma unroll
    for (int c = 0; c < 16; ++c) {
      float4 qf[4], kf[4];
#pragma unroll
      for (int i = 0; i < 4; ++i) {
        int r = ty * 4 + i;
        qf[i] = *(const float4*)&Qs[r][SWZ(r, c)];
      }
#pragma unroll
      for (int j = 0; j < 4; ++j) {
        int r = tx * 4 + j;
        kf[j] = *(const float4*)&Ks[r][SWZ(r, c)];
      }
#pragma unroll
      for (int i = 0; i < 4; ++i)
#pragma unroll
        for (int j = 0; j < 4; ++j)
          s[i][j] += dot4(qf[i], kf[j]);
    }

#pragma unroll
    for (int i = 0; i < 4; ++i) {
      float mq = mln[((size_t)(b * HH + h)) * SS + q0 + ty * 4 + i];
      av[i][0] += __expf(s[i][0] - mq);
      av[i][1] += __expf(s[i][1] - mq);
      av[i][2] += __expf(s[i][2] - mq);
      av[i][3] += __expf(s[i][3] - mq);
    }
  }

  const float ih = 1.f / HH;
#pragma unroll
  for (int i = 0; i < 4; ++i) {
    float4 o = {av[i][0] * ih, av[i][1] * ih, av[i][2] * ih, av[i][3] * ih};
    *(float4*)&avg[(size_t)(b * SS + q0 + ty * 4 + i) * SS + k0 + tx * 4] = o;
  }
}

// ---------------------------------------------------------------------------
extern "C" void kernel_launch(void* const* d_in, const int* in_sizes, int n_in,
                              void* d_out, int out_size, void* d_ws, size_t ws_size,
                              hipStream_t stream) {
  const float* q  = (const float*)d_in[0];
  const float* k  = (const float*)d_in[1];
  const float* v  = (const float*)d_in[2];
  const float* Wq = (const float*)d_in[3];
  const float* bq = (const float*)d_in[4];
  const float* Wk = (const float*)d_in[5];
  const float* bk = (const float*)d_in[6];
  const float* Wv = (const float*)d_in[7];
  const float* bv = (const float*)d_in[8];
  const float* Wo = (const float*)d_in[9];
  const float* bo = (const float*)d_in[10];

  float* ws  = (float*)d_ws;
  float* Q   = ws;                 // [4096,1024]
  float* K   = ws + 4194304;       // [4096,1024]
  float* V   = ws + 8388608;       // [4096,1024]
  float* att = ws + 12582912;      // [4096,1024]

  float* outp = (float*)d_out;           // output [B,S,E]
  float* avg  = outp + 4194304;          // avg_attn [B,S,S]
  // mln[B,H,S] (256 KB) lives in the output region; k_avg consumes it BEFORE
  // k_gemm_o overwrites the region (stream-ordered). Zero extra ws needed.
  float* mln  = outp;

  dim3 gqkv(EE / 128, NROW / 128, 3);    // (8,32,3)
  k_gemm_qkv<<<gqkv, 256, 0, stream>>>(q, k, v, Wq, Wk, Wv, bq, bk, bv, Q, K, V);

  dim3 gfl(SS / 64, HH, BB);             // (32,16,2) = 1024 blocks
  k_flash<<<gfl, 256, 0, stream>>>(Q, K, V, att, mln);

  dim3 gav(SS / 64, SS / 64, BB);        // (32,32,2) = 2048 blocks
  k_avg<<<gav, 256, 0, stream>>>(Q, K, mln, avg);

  dim3 go(EE / 128, NROW / 128);         // (8,32)
  k_gemm_o<<<go, 256, 0, stream>>>(att, Wo, bo, outp);
}

// Round 7
// 1610.237 us; speedup vs baseline: 2.0698x; 1.2599x over previous
//
#include <hip/hip_runtime.h>
#include <hip/hip_bf16.h>
#include <math.h>

#define BB 2
#define SS 2048
#define EE 1024
#define HH 16
#define DD 64
#define NROW (BB*SS)
#define SCALE 0.125f

__device__ __forceinline__ float dot4(float4 a, float4 b){
  return a.x*b.x + a.y*b.y + a.z*b.z + a.w*b.w;
}

// ---------------------------------------------------------------------------
// GEMM: out = X @ W.T + b  (unchanged; proven correct, not current bottleneck)
// ---------------------------------------------------------------------------
__device__ __forceinline__ void gemm_body(const float* __restrict__ X,
                                          const float* __restrict__ W,
                                          const float* __restrict__ bias,
                                          float* __restrict__ out)
{
  __shared__ float sA[32][128];
  __shared__ float sB[32][128];
  const int tid = threadIdx.x;
  const int tm = tid >> 4;
  const int tn = tid & 15;
  const int m0 = blockIdx.y * 128;
  const int n0 = blockIdx.x * 128;

  float acc[8][8];
#pragma unroll
  for (int i = 0; i < 8; ++i)
#pragma unroll
    for (int j = 0; j < 8; ++j) acc[i][j] = 0.f;

  for (int kt = 0; kt < EE; kt += 32) {
    __syncthreads();
#pragma unroll
    for (int s = 0; s < 4; ++s) {
      int slot = tid + s * 256;
      int row  = slot >> 3;
      int c4   = slot & 7;
      float4 av = *(const float4*)&X[(size_t)(m0 + row) * EE + kt + c4 * 4];
      float4 bv = *(const float4*)&W[(size_t)(n0 + row) * EE + kt + c4 * 4];
#pragma unroll
      for (int j = 0; j < 4; ++j) {
        int k  = c4 * 4 + j;
        int ch = (row >> 2) ^ (k & 31);
        sA[k][ch * 4 + (row & 3)] = ((const float*)&av)[j];
        sB[k][ch * 4 + (row & 3)] = ((const float*)&bv)[j];
      }
    }
    __syncthreads();
#pragma unroll
    for (int k = 0; k < 32; ++k) {
      const int sw = k & 31;
      float4 a0 = *(const float4*)&sA[k][((tm        ^ sw)) * 4];
      float4 a1 = *(const float4*)&sA[k][(((16 + tm) ^ sw)) * 4];
      float4 b0 = *(const float4*)&sB[k][((tn        ^ sw)) * 4];
      float4 b1 = *(const float4*)&sB[k][(((16 + tn) ^ sw)) * 4];
      float a[8]  = {a0.x, a0.y, a0.z, a0.w, a1.x, a1.y, a1.z, a1.w};
      float bb[8] = {b0.x, b0.y, b0.z, b0.w, b1.x, b1.y, b1.z, b1.w};
#pragma unroll
      for (int i = 0; i < 8; ++i)
#pragma unroll
        for (int j = 0; j < 8; ++j)
          acc[i][j] = fmaf(a[i], bb[j], acc[i][j]);
    }
  }

  float4 bi0 = *(const float4*)&bias[n0 + tn * 4];
  float4 bi1 = *(const float4*)&bias[n0 + 64 + tn * 4];
#pragma unroll
  for (int i = 0; i < 8; ++i) {
    int m = m0 + ((i < 4) ? (tm * 4 + i) : (64 + tm * 4 + (i - 4)));
    float4 o0 = {acc[i][0] + bi0.x, acc[i][1] + bi0.y,
                 acc[i][2] + bi0.z, acc[i][3] + bi0.w};
    float4 o1 = {acc[i][4] + bi1.x, acc[i][5] + bi1.y,
                 acc[i][6] + bi1.z, acc[i][7] + bi1.w};
    *(float4*)&out[(size_t)m * EE + n0 + tn * 4]      = o0;
    *(float4*)&out[(size_t)m * EE + n0 + 64 + tn * 4] = o1;
  }
}

__global__ __launch_bounds__(256) void k_gemm_qkv(
    const float* __restrict__ xq, const float* __restrict__ xk,
    const float* __restrict__ xv,
    const float* __restrict__ Wq, const float* __restrict__ Wk,
    const float* __restrict__ Wv,
    const float* __restrict__ bq, const float* __restrict__ bk,
    const float* __restrict__ bv,
    float* __restrict__ Q, float* __restrict__ K, float* __restrict__ V)
{
  const int z = blockIdx.z;
  const float* X = (z == 0) ? xq : (z == 1) ? xk : xv;
  const float* W = (z == 0) ? Wq : (z == 1) ? Wk : Wv;
  const float* b = (z == 0) ? bq : (z == 1) ? bk : bv;
  float*       O = (z == 0) ? Q  : (z == 1) ? K  : V;
  gemm_body(X, W, b, O);
}

__global__ __launch_bounds__(256) void k_gemm_o(
    const float* __restrict__ att, const float* __restrict__ Wo,
    const float* __restrict__ bo, float* __restrict__ out)
{
  gemm_body(att, Wo, bo, out);
}

// ---------------------------------------------------------------------------
// LDS swizzle for [64][64] fp32 tiles accessed as float4 chunks.
// phys chunk = c ^ ((r>>2) & 15).  Phase-conflict-free for:
//   staging writes (lane map c=tid&15, r=u*16+(tid>>4)): chunk = c ^ const
//   K-frag reads  (r=4*tx+j):  chunk = c ^ tx   -> 8 distinct per phase
//   V-frag reads  (r=4*kk+kc): chunk = tx ^ kk  -> 8 distinct per phase
//   pS writes     (r=4*ty+i, c=tx): chunk = tx ^ ty -> 8 distinct per phase
//   Q/pS broadcast reads: same addr per phase (free)
// ---------------------------------------------------------------------------
#define SWZ4(r, c) ((((c) ^ (((r) >> 2) & 15))) * 4)

// ---------------------------------------------------------------------------
// k_flash: flash attention, one (b, h, 64-row q-tile) per block, 256 thr.
// Online softmax; writes att[b,q,h*64+d] and mln[b,h,q] = m + ln(l).
// K/V global loads for tile t+1 prefetched into regs during tile t compute.
// ---------------------------------------------------------------------------
__global__ __launch_bounds__(256) void k_flash(
    const float* __restrict__ Qg, const float* __restrict__ Kg,
    const float* __restrict__ Vg,
    float* __restrict__ att, float* __restrict__ mln)
{
  __shared__ float Qs[64][64];
  __shared__ float Ks[64][64];
  __shared__ float Vs[64][64];
  __shared__ float pS[64][64];

  const int tid = threadIdx.x;
  const int ty  = tid >> 4;   // 0..15 -> q rows ty*4..+3
  const int tx  = tid & 15;   // 0..15 -> k / d cols tx*4..+3
  const int sc_ = tid & 15;   // staging chunk
  const int sr_ = tid >> 4;   // staging row base
  const int q0  = blockIdx.x * 64;
  const int h   = blockIdx.y;
  const int b   = blockIdx.z;

  const float* Qb = Qg + (size_t)b * SS * EE + h * 64;
  const float* Kb = Kg + (size_t)b * SS * EE + h * 64;
  const float* Vb = Vg + (size_t)b * SS * EE + h * 64;

  // stage Q tile (scaled); lane map: chunk sc_, rows u*16+sr_
#pragma unroll
  for (int u = 0; u < 4; ++u) {
    int r = u * 16 + sr_;
    float4 v = *(const float4*)&Qb[(size_t)(q0 + r) * EE + sc_ * 4];
    v.x *= SCALE; v.y *= SCALE; v.z *= SCALE; v.w *= SCALE;
    *(float4*)&Qs[r][SWZ4(r, sc_)] = v;
  }

  // prefetch K/V tile 0 into regs
  float4 kreg[4], vreg[4];
#pragma unroll
  for (int u = 0; u < 4; ++u) {
    int r = u * 16 + sr_;
    kreg[u] = *(const float4*)&Kb[(size_t)r * EE + sc_ * 4];
    vreg[u] = *(const float4*)&Vb[(size_t)r * EE + sc_ * 4];
  }

  float m[4] = {-1e30f, -1e30f, -1e30f, -1e30f};
  float l[4] = {0.f, 0.f, 0.f, 0.f};
  float acc[4][4];
#pragma unroll
  for (int i = 0; i < 4; ++i)
#pragma unroll
    for (int j = 0; j < 4; ++j) acc[i][j] = 0.f;

  for (int kt = 0; kt < SS; kt += 64) {
    __syncthreads();   // prev iteration's Ks/Vs/pS readers done
#pragma unroll
    for (int u = 0; u < 4; ++u) {
      int r = u * 16 + sr_;
      *(float4*)&Ks[r][SWZ4(r, sc_)] = kreg[u];
      *(float4*)&Vs[r][SWZ4(r, sc_)] = vreg[u];
    }
    __syncthreads();

    // issue next-tile global loads; latency hides under QK+softmax+PV
    if (kt + 64 < SS) {
#pragma unroll
      for (int u = 0; u < 4; ++u) {
        int r = kt + 64 + u * 16 + sr_;
        kreg[u] = *(const float4*)&Kb[(size_t)r * EE + sc_ * 4];
        vreg[u] = *(const float4*)&Vb[(size_t)r * EE + sc_ * 4];
      }
    }

    // s-tile: 4q x 4k per thread
    float s[4][4] = {{0,0,0,0},{0,0,0,0},{0,0,0,0},{0,0,0,0}};
#pragma unroll
    for (int c = 0; c < 16; ++c) {
      float4 qf[4], kf[4];
#pragma unroll
      for (int i = 0; i < 4; ++i)
        qf[i] = *(const float4*)&Qs[ty * 4 + i][((c ^ ty)) * 4];
#pragma unroll
      for (int j = 0; j < 4; ++j)
        kf[j] = *(const float4*)&Ks[tx * 4 + j][((c ^ tx)) * 4];
#pragma unroll
      for (int i = 0; i < 4; ++i)
#pragma unroll
        for (int j = 0; j < 4; ++j)
          s[i][j] += dot4(qf[i], kf[j]);
    }

    // online softmax update per q-row (reduce over the 16 tx lanes)
#pragma unroll
    for (int i = 0; i < 4; ++i) {
      float tmax = fmaxf(fmaxf(s[i][0], s[i][1]), fmaxf(s[i][2], s[i][3]));
#pragma unroll
      for (int off = 8; off >= 1; off >>= 1)
        tmax = fmaxf(tmax, __shfl_xor(tmax, off));
      float mn = fmaxf(m[i], tmax);
      float sc = __expf(m[i] - mn);
      float p0 = __expf(s[i][0] - mn);
      float p1 = __expf(s[i][1] - mn);
      float p2 = __expf(s[i][2] - mn);
      float p3 = __expf(s[i][3] - mn);
      s[i][0] = p0; s[i][1] = p1; s[i][2] = p2; s[i][3] = p3;
      float tsum = p0 + p1 + p2 + p3;
#pragma unroll
      for (int off = 8; off >= 1; off >>= 1)
        tsum += __shfl_xor(tsum, off);
      l[i] = l[i] * sc + tsum;
      m[i] = mn;
      acc[i][0] *= sc; acc[i][1] *= sc; acc[i][2] *= sc; acc[i][3] *= sc;
      *(float4*)&pS[ty * 4 + i][((tx ^ ty)) * 4] = *(float4*)&s[i][0];
    }
    __syncthreads();

    // PV: acc[4q][4d] += pS[64q][64k] @ Vs[64k][4d]
#pragma unroll
    for (int kk = 0; kk < 16; ++kk) {
      float4 pf[4], vf[4];
#pragma unroll
      for (int i = 0; i < 4; ++i)
        pf[i] = *(const float4*)&pS[ty * 4 + i][((kk ^ ty)) * 4];
#pragma unroll
      for (int kc = 0; kc < 4; ++kc)
        vf[kc] = *(const float4*)&Vs[kk * 4 + kc][((tx ^ kk)) * 4];
#pragma unroll
      for (int i = 0; i < 4; ++i) {
        const float pa[4] = {pf[i].x, pf[i].y, pf[i].z, pf[i].w};
#pragma unroll
        for (int kc = 0; kc < 4; ++kc) {
          acc[i][0] = fmaf(pa[kc], vf[kc].x, acc[i][0]);
          acc[i][1] = fmaf(pa[kc], vf[kc].y, acc[i][1]);
          acc[i][2] = fmaf(pa[kc], vf[kc].z, acc[i][2]);
          acc[i][3] = fmaf(pa[kc], vf[kc].w, acc[i][3]);
        }
      }
    }
  }

  // epilogue
#pragma unroll
  for (int i = 0; i < 4; ++i) {
    int q = q0 + ty * 4 + i;
    float inv = 1.f / l[i];
    float4 o = {acc[i][0] * inv, acc[i][1] * inv, acc[i][2] * inv, acc[i][3] * inv};
    *(float4*)&att[(size_t)(b * SS + q) * EE + h * 64 + tx * 4] = o;
    if (tx == 0)
      mln[((size_t)(b * HH + h)) * SS + q] = m[i] + __logf(l[i]);
  }
}

// ---------------------------------------------------------------------------
// k_avg: one block per (b, 64q x 64k tile); loops 16 heads, recomputes scores,
// p = exp(s - mln), accumulates avg in registers, single write (no RMW/race).
// Same SWZ4 layout + reg prefetch; mln staged to LDS once.
// ---------------------------------------------------------------------------
__global__ __launch_bounds__(256) void k_avg(
    const float* __restrict__ Qg, const float* __restrict__ Kg,
    const float* __restrict__ mln, float* __restrict__ avg)
{
  __shared__ float Qs[64][64];
  __shared__ float Ks[64][64];
  __shared__ float mlnS[16][64];

  const int tid = threadIdx.x;
  const int ty  = tid >> 4;
  const int tx  = tid & 15;
  const int sc_ = tid & 15;
  const int sr_ = tid >> 4;
  const int k0  = blockIdx.x * 64;
  const int q0  = blockIdx.y * 64;
  const int b   = blockIdx.z;

  // stage mln[b, h, q0..q0+63] for all 16 heads (4 KB); thread t: h=t>>4, 4 rows
  {
    int hh = tid >> 4, r4 = (tid & 15) * 4;
    *(float4*)&mlnS[hh][r4] =
        *(const float4*)&mln[((size_t)(b * HH + hh)) * SS + q0 + r4];
  }

  float av[4][4];
#pragma unroll
  for (int i = 0; i < 4; ++i)
#pragma unroll
    for (int j = 0; j < 4; ++j) av[i][j] = 0.f;

  // prefetch h=0 tiles
  float4 qreg[4], kreg[4];
#pragma unroll
  for (int u = 0; u < 4; ++u) {
    int r = u * 16 + sr_;
    qreg[u] = *(const float4*)&Qg[(size_t)(b * SS + q0 + r) * EE + sc_ * 4];
    kreg[u] = *(const float4*)&Kg[(size_t)(b * SS + k0 + r) * EE + sc_ * 4];
  }

  for (int h = 0; h < HH; ++h) {
    __syncthreads();   // prev h readers done (also covers mlnS staging at h=0)
#pragma unroll
    for (int u = 0; u < 4; ++u) {
      int r = u * 16 + sr_;
      float4 qv = qreg[u];
      qv.x *= SCALE; qv.y *= SCALE; qv.z *= SCALE; qv.w *= SCALE;
      *(float4*)&Qs[r][SWZ4(r, sc_)] = qv;
      *(float4*)&Ks[r][SWZ4(r, sc_)] = kreg[u];
    }
    __syncthreads();

    if (h + 1 < HH) {
      const float* Qb = Qg + (size_t)b * SS * EE + (h + 1) * 64;
      const float* Kb = Kg + (size_t)b * SS * EE + (h + 1) * 64;
#pragma unroll
      for (int u = 0; u < 4; ++u) {
        int r = u * 16 + sr_;
        qreg[u] = *(const float4*)&Qb[(size_t)(q0 + r) * EE + sc_ * 4];
        kreg[u] = *(const float4*)&Kb[(size_t)(k0 + r) * EE + sc_ * 4];
      }
    }

    float s[4][4] = {{0,0,0,0},{0,0,0,0},{0,0,0,0},{0,0,0,0}};
#pragma unroll
    for (int c = 0; c < 16; ++c) {
      float4 qf[4], kf[4];
#pragma unroll
      for (int i = 0; i < 4; ++i)
        qf[i] = *(const float4*)&Qs[ty * 4 + i][((c ^ ty)) * 4];
#pragma unroll
      for (int j = 0; j < 4; ++j)
        kf[j] = *(const float4*)&Ks[tx * 4 + j][((c ^ tx)) * 4];
#pragma unroll
      for (int i = 0; i < 4; ++i)
#pragma unroll
        for (int j = 0; j < 4; ++j)
          s[i][j] += dot4(qf[i], kf[j]);
    }

#pragma unroll
    for (int i = 0; i < 4; ++i) {
      float mq = mlnS[h][ty * 4 + i];
      av[i][0] += __expf(s[i][0] - mq);
      av[i][1] += __expf(s[i][1] - mq);
      av[i][2] += __expf(s[i][2] - mq);
      av[i][3] += __expf(s[i][3] - mq);
    }
  }

  const float ih = 1.f / HH;
#pragma unroll
  for (int i = 0; i < 4; ++i) {
    float4 o = {av[i][0] * ih, av[i][1] * ih, av[i][2] * ih, av[i][3] * ih};
    *(float4*)&avg[(size_t)(b * SS + q0 + ty * 4 + i) * SS + k0 + tx * 4] = o;
  }
}

// ---------------------------------------------------------------------------
extern "C" void kernel_launch(void* const* d_in, const int* in_sizes, int n_in,
                              void* d_out, int out_size, void* d_ws, size_t ws_size,
                              hipStream_t stream) {
  const float* q  = (const float*)d_in[0];
  const float* k  = (const float*)d_in[1];
  const float* v  = (const float*)d_in[2];
  const float* Wq = (const float*)d_in[3];
  const float* bq = (const float*)d_in[4];
  const float* Wk = (const float*)d_in[5];
  const float* bk = (const float*)d_in[6];
  const float* Wv = (const float*)d_in[7];
  const float* bv = (const float*)d_in[8];
  const float* Wo = (const float*)d_in[9];
  const float* bo = (const float*)d_in[10];

  float* ws  = (float*)d_ws;
  float* Q   = ws;                 // [4096,1024]
  float* K   = ws + 4194304;       // [4096,1024]
  float* V   = ws + 8388608;       // [4096,1024]
  float* att = ws + 12582912;      // [4096,1024]

  float* outp = (float*)d_out;           // output [B,S,E]
  float* avg  = outp + 4194304;          // avg_attn [B,S,S]
  // mln[B,H,S] (256 KB) lives in the output region; k_avg consumes it BEFORE
  // k_gemm_o overwrites the region (stream-ordered). Zero extra ws needed.
  float* mln  = outp;

  dim3 gqkv(EE / 128, NROW / 128, 3);    // (8,32,3)
  k_gemm_qkv<<<gqkv, 256, 0, stream>>>(q, k, v, Wq, Wk, Wv, bq, bk, bv, Q, K, V);

  dim3 gfl(SS / 64, HH, BB);             // (32,16,2) = 1024 blocks
  k_flash<<<gfl, 256, 0, stream>>>(Q, K, V, att, mln);

  dim3 gav(SS / 64, SS / 64, BB);        // (32,32,2) = 2048 blocks
  k_avg<<<gav, 256, 0, stream>>>(Q, K, mln, avg);

  dim3 go(EE / 128, NROW / 128);         // (8,32)
  k_gemm_o<<<go, 256, 0, stream>>>(att, Wo, bo, outp);
}

// Round 8
// 1067.202 us; speedup vs baseline: 3.1229x; 1.5088x over previous
//
#include <hip/hip_runtime.h>
#include <hip/hip_bf16.h>
#include <math.h>

#define BB 2
#define SS 2048
#define EE 1024
#define HH 16
#define DD 64
#define NROW (BB*SS)
#define SCALE 0.125f

typedef float f32x4 __attribute__((ext_vector_type(4)));
typedef __bf16 bf16x8 __attribute__((ext_vector_type(8)));

__device__ __forceinline__ f32x4 MFMA(bf16x8 a, bf16x8 b, f32x4 c){
  return __builtin_amdgcn_mfma_f32_16x16x32_bf16(a, b, c, 0, 0, 0);
}
__device__ __forceinline__ unsigned short f2bf(float x){   // RTN-even
  unsigned u = __builtin_bit_cast(unsigned, x);
  u = (u + 0x7FFFu + ((u >> 16) & 1u)) >> 16;
  return (unsigned short)u;
}
__device__ __forceinline__ float bf2f(unsigned short h){
  unsigned u = ((unsigned)h) << 16;
  return __builtin_bit_cast(float, u);
}
__device__ __forceinline__ f32x4 zero4(){
  f32x4 z; z[0]=0.f; z[1]=0.f; z[2]=0.f; z[3]=0.f; return z;
}

// LDS swizzles for [64][64] bf16 tiles (row stride 128B).
// swzK: 16B-slot XOR — conflict-free b128 reads where 16 lanes read 16 rows
//        at the same column range (K tiles, V^T tiles).
__device__ __forceinline__ int swzK(int row, int col){
  return row * 64 + (col ^ ((row & 7) << 3));
}
// swzP: XOR + row-rotate — 2-way on both the C-layout scalar writes and the
//        A-fragment b128 reads of the P tile (verified lane-by-lane).
__device__ __forceinline__ int swzP(int row, int col){
  int slot = ((col >> 3) ^ (row & 7)) + 2 * ((row >> 2) & 3);
  return row * 64 + ((slot & 7) << 3) + (col & 7);
}

// ---------------------------------------------------------------------------
// GEMM: out = X @ W.T + b. MODE 0: fp32 out. MODE 1: (acc+bias)*scale split
// into hi/lo bf16 arrays (hi = bf16 RTN, lo = bf16(x - hi)).
// ---------------------------------------------------------------------------
template<int MODE>
__device__ __forceinline__ void gemm_body(const float* __restrict__ X,
                                          const float* __restrict__ W,
                                          const float* __restrict__ bias,
                                          float* __restrict__ outf,
                                          unsigned short* __restrict__ oh,
                                          unsigned short* __restrict__ ol,
                                          float scale)
{
  __shared__ float sA[32][128];
  __shared__ float sB[32][128];
  const int tid = threadIdx.x;
  const int tm = tid >> 4;
  const int tn = tid & 15;
  const int m0 = blockIdx.y * 128;
  const int n0 = blockIdx.x * 128;

  float acc[8][8];
#pragma unroll
  for (int i = 0; i < 8; ++i)
#pragma unroll
    for (int j = 0; j < 8; ++j) acc[i][j] = 0.f;

  for (int kt = 0; kt < EE; kt += 32) {
    __syncthreads();
#pragma unroll
    for (int s = 0; s < 4; ++s) {
      int slot = tid + s * 256;
      int row  = slot >> 3;
      int c4   = slot & 7;
      float4 av = *(const float4*)&X[(size_t)(m0 + row) * EE + kt + c4 * 4];
      float4 bv = *(const float4*)&W[(size_t)(n0 + row) * EE + kt + c4 * 4];
#pragma unroll
      for (int j = 0; j < 4; ++j) {
        int k  = c4 * 4 + j;
        int ch = (row >> 2) ^ (k & 31);
        sA[k][ch * 4 + (row & 3)] = ((const float*)&av)[j];
        sB[k][ch * 4 + (row & 3)] = ((const float*)&bv)[j];
      }
    }
    __syncthreads();
#pragma unroll
    for (int k = 0; k < 32; ++k) {
      const int sw = k & 31;
      float4 a0 = *(const float4*)&sA[k][((tm        ^ sw)) * 4];
      float4 a1 = *(const float4*)&sA[k][(((16 + tm) ^ sw)) * 4];
      float4 b0 = *(const float4*)&sB[k][((tn        ^ sw)) * 4];
      float4 b1 = *(const float4*)&sB[k][(((16 + tn) ^ sw)) * 4];
      float a[8]  = {a0.x, a0.y, a0.z, a0.w, a1.x, a1.y, a1.z, a1.w};
      float bb[8] = {b0.x, b0.y, b0.z, b0.w, b1.x, b1.y, b1.z, b1.w};
#pragma unroll
      for (int i = 0; i < 8; ++i)
#pragma unroll
        for (int j = 0; j < 8; ++j)
          acc[i][j] = fmaf(a[i], bb[j], acc[i][j]);
    }
  }

  float4 bi0 = *(const float4*)&bias[n0 + tn * 4];
  float4 bi1 = *(const float4*)&bias[n0 + 64 + tn * 4];
#pragma unroll
  for (int i = 0; i < 8; ++i) {
    int m = m0 + ((i < 4) ? (tm * 4 + i) : (64 + tm * 4 + (i - 4)));
    float v0[4] = {acc[i][0] + bi0.x, acc[i][1] + bi0.y,
                   acc[i][2] + bi0.z, acc[i][3] + bi0.w};
    float v1[4] = {acc[i][4] + bi1.x, acc[i][5] + bi1.y,
                   acc[i][6] + bi1.z, acc[i][7] + bi1.w};
    if (MODE == 0) {
      *(float4*)&outf[(size_t)m * EE + n0 + tn * 4]      = {v0[0], v0[1], v0[2], v0[3]};
      *(float4*)&outf[(size_t)m * EE + n0 + 64 + tn * 4] = {v1[0], v1[1], v1[2], v1[3]};
    } else {
      ushort4 h0, l0, h1, l1;
      unsigned short* ph0 = (unsigned short*)&h0;
      unsigned short* pl0 = (unsigned short*)&l0;
      unsigned short* ph1 = (unsigned short*)&h1;
      unsigned short* pl1 = (unsigned short*)&l1;
#pragma unroll
      for (int j = 0; j < 4; ++j) {
        float a0s = v0[j] * scale;
        unsigned short hh = f2bf(a0s);
        ph0[j] = hh; pl0[j] = f2bf(a0s - bf2f(hh));
        float a1s = v1[j] * scale;
        unsigned short h2 = f2bf(a1s);
        ph1[j] = h2; pl1[j] = f2bf(a1s - bf2f(h2));
      }
      *(ushort4*)&oh[(size_t)m * EE + n0 + tn * 4]      = h0;
      *(ushort4*)&ol[(size_t)m * EE + n0 + tn * 4]      = l0;
      *(ushort4*)&oh[(size_t)m * EE + n0 + 64 + tn * 4] = h1;
      *(ushort4*)&ol[(size_t)m * EE + n0 + 64 + tn * 4] = l1;
    }
  }
}

__global__ __launch_bounds__(256) void k_gemm_qkv(
    const float* __restrict__ xq, const float* __restrict__ xk,
    const float* __restrict__ xv,
    const float* __restrict__ Wq, const float* __restrict__ Wk,
    const float* __restrict__ Wv,
    const float* __restrict__ bq, const float* __restrict__ bk,
    const float* __restrict__ bv,
    unsigned short* __restrict__ Qhp, unsigned short* __restrict__ Qlp,
    unsigned short* __restrict__ Khp, unsigned short* __restrict__ Klp,
    unsigned short* __restrict__ Vhp, unsigned short* __restrict__ Vlp)
{
  const int z = blockIdx.z;
  const float* X = (z == 0) ? xq : (z == 1) ? xk : xv;
  const float* W = (z == 0) ? Wq : (z == 1) ? Wk : Wv;
  const float* b = (z == 0) ? bq : (z == 1) ? bk : bv;
  unsigned short* oh = (z == 0) ? Qhp : (z == 1) ? Khp : Vhp;
  unsigned short* ol = (z == 0) ? Qlp : (z == 1) ? Klp : Vlp;
  const float scale = (z == 0) ? SCALE : 1.0f;   // fold Q scaling here
  gemm_body<1>(X, W, b, nullptr, oh, ol, scale);
}

__global__ __launch_bounds__(256) void k_gemm_o(
    const float* __restrict__ att, const float* __restrict__ Wo,
    const float* __restrict__ bo, float* __restrict__ out)
{
  gemm_body<0>(att, Wo, bo, out, nullptr, nullptr, 1.0f);
}

// ---------------------------------------------------------------------------
// k_flash: MFMA flash attention. Block = (b, h, 64 q-rows), 4 waves; wave w
// owns the 16-row q-strip 16w. QK^T and PV via mfma_f32_16x16x32_bf16 with
// hi/lo split operands (3 MFMA per product tile -> ~fp32 accuracy).
// A-frag (row=l&15, k=(l>>4)*8+e), B-frag (col=l&15, k likewise),
// C/D (col=l&15, row=(l>>4)*4+reg). P round-trips C-layout -> LDS -> A-layout.
// ---------------------------------------------------------------------------
__global__ __launch_bounds__(256) void k_flash(
    const unsigned short* __restrict__ Qh, const unsigned short* __restrict__ Ql,
    const unsigned short* __restrict__ Kh, const unsigned short* __restrict__ Kl,
    const unsigned short* __restrict__ Vh, const unsigned short* __restrict__ Vl,
    float* __restrict__ att, float* __restrict__ mln)
{
  __shared__ __align__(16) unsigned short KsH[64 * 64], KsL[64 * 64];
  __shared__ __align__(16) unsigned short VtH[64 * 64], VtL[64 * 64];
  __shared__ __align__(16) unsigned short pSH[64 * 64], pSL[64 * 64];

  const int tid  = threadIdx.x;
  const int lane = tid & 63;
  const int w    = tid >> 6;
  const int l15  = lane & 15;
  const int l4   = lane >> 4;
  const int q0   = blockIdx.x * 64;
  const int h    = blockIdx.y;
  const int b    = blockIdx.z;

  const size_t hb = (size_t)b * SS * EE + h * 64;

  // Q A-frags for this wave's strip (rows q0+16w+l15), both 32-k chunks, hi+lo
  const size_t qoff = hb + (size_t)(q0 + 16 * w + l15) * EE + l4 * 8;
  const bf16x8 qh0 = *(const bf16x8*)&Qh[qoff];
  const bf16x8 qh1 = *(const bf16x8*)&Qh[qoff + 32];
  const bf16x8 ql0 = *(const bf16x8*)&Ql[qoff];
  const bf16x8 ql1 = *(const bf16x8*)&Ql[qoff + 32];

  // staging map: row sr = tid>>2 (0..63), 16B slots s1 = tid&3 and s1+4
  const int sr = tid >> 2;
  const int s1 = tid & 3;
  const int s2 = s1 + 4;

  uint4 krh[2], krl[2], vrh[2], vrl[2];
  {
    const size_t ko = hb + (size_t)sr * EE;
    krh[0] = *(const uint4*)&Kh[ko + s1 * 8]; krh[1] = *(const uint4*)&Kh[ko + s2 * 8];
    krl[0] = *(const uint4*)&Kl[ko + s1 * 8]; krl[1] = *(const uint4*)&Kl[ko + s2 * 8];
    vrh[0] = *(const uint4*)&Vh[ko + s1 * 8]; vrh[1] = *(const uint4*)&Vh[ko + s2 * 8];
    vrl[0] = *(const uint4*)&Vl[ko + s1 * 8]; vrl[1] = *(const uint4*)&Vl[ko + s2 * 8];
  }

  float m[4]    = {-1e30f, -1e30f, -1e30f, -1e30f};
  float lsum[4] = {0.f, 0.f, 0.f, 0.f};
  f32x4 acco[4];
#pragma unroll
  for (int t = 0; t < 4; ++t) acco[t] = zero4();

  for (int kt = 0; kt < SS; kt += 64) {
    __syncthreads();   // prior iteration's LDS readers done
    {
      *(uint4*)&KsH[swzK(sr, s1 * 8)] = krh[0];
      *(uint4*)&KsH[swzK(sr, s2 * 8)] = krh[1];
      *(uint4*)&KsL[swzK(sr, s1 * 8)] = krl[0];
      *(uint4*)&KsL[swzK(sr, s2 * 8)] = krl[1];
      // V transpose scatter: Vt[d][k] <- V[k=sr][d]
#pragma unroll
      for (int u = 0; u < 2; ++u) {
        const int d0 = (u ? s2 : s1) * 8;
        const unsigned short* pv = (const unsigned short*)&vrh[u];
        const unsigned short* pw = (const unsigned short*)&vrl[u];
#pragma unroll
        for (int e = 0; e < 8; ++e) {
          const int idx = swzK(d0 + e, sr);
          VtH[idx] = pv[e];
          VtL[idx] = pw[e];
        }
      }
    }
    __syncthreads();

    // prefetch next tile into regs; latency hides under MFMA+softmax
    if (kt + 64 < SS) {
      const size_t ko = hb + (size_t)(kt + 64 + sr) * EE;
      krh[0] = *(const uint4*)&Kh[ko + s1 * 8]; krh[1] = *(const uint4*)&Kh[ko + s2 * 8];
      krl[0] = *(const uint4*)&Kl[ko + s1 * 8]; krl[1] = *(const uint4*)&Kl[ko + s2 * 8];
      vrh[0] = *(const uint4*)&Vh[ko + s1 * 8]; vrh[1] = *(const uint4*)&Vh[ko + s2 * 8];
      vrl[0] = *(const uint4*)&Vl[ko + s1 * 8]; vrl[1] = *(const uint4*)&Vl[ko + s2 * 8];
    }

    // ---- QK^T: accs[t] = S[16q x 16k tile t], hi/lo 3-term ----
    f32x4 accs[4];
#pragma unroll
    for (int t = 0; t < 4; ++t) accs[t] = zero4();
#pragma unroll
    for (int t = 0; t < 4; ++t) {
      const int krow = 16 * t + l15;
#pragma unroll
      for (int c = 0; c < 2; ++c) {
        const int ko = swzK(krow, (c * 4 + l4) * 8);
        const bf16x8 bh = *(const bf16x8*)&KsH[ko];
        const bf16x8 bl = *(const bf16x8*)&KsL[ko];
        const bf16x8 qa = c ? qh1 : qh0;
        const bf16x8 qb = c ? ql1 : ql0;
        accs[t] = MFMA(qa, bh, accs[t]);
        accs[t] = MFMA(qa, bl, accs[t]);
        accs[t] = MFMA(qb, bh, accs[t]);
      }
    }

    // ---- online softmax (rows = 16w + l4*4 + r, reduce over 16 l15 lanes) ----
    const int prow_base = 16 * w + l4 * 4;
#pragma unroll
    for (int r = 0; r < 4; ++r) {
      float tmax = fmaxf(fmaxf(accs[0][r], accs[1][r]),
                         fmaxf(accs[2][r], accs[3][r]));
#pragma unroll
      for (int off = 8; off >= 1; off >>= 1)
        tmax = fmaxf(tmax, __shfl_xor(tmax, off));
      const float mn = fmaxf(m[r], tmax);
      const float sc = __expf(m[r] - mn);
      float pv[4];
      float ts = 0.f;
#pragma unroll
      for (int t = 0; t < 4; ++t) { pv[t] = __expf(accs[t][r] - mn); ts += pv[t]; }
#pragma unroll
      for (int off = 8; off >= 1; off >>= 1)
        ts += __shfl_xor(ts, off);
      lsum[r] = lsum[r] * sc + ts;
      m[r] = mn;
      const int prow = prow_base + r;
#pragma unroll
      for (int t = 0; t < 4; ++t) {
        const unsigned short hi = f2bf(pv[t]);
        const unsigned short lo = f2bf(pv[t] - bf2f(hi));
        const int idx = swzP(prow, 16 * t + l15);
        pSH[idx] = hi;
        pSL[idx] = lo;
      }
#pragma unroll
      for (int t = 0; t < 4; ++t) acco[t][r] *= sc;
    }

    // ---- PV: acco[t_d] += P[16q x 64k] * V[64k x 16d]; pS is wave-private
    // (wave reads exactly the rows it wrote -> no barrier, lgkmcnt orders) ----
    const int parow = 16 * w + l15;
#pragma unroll
    for (int kc = 0; kc < 2; ++kc) {
      const int po = swzP(parow, kc * 32 + l4 * 8);
      const bf16x8 pah = *(const bf16x8*)&pSH[po];
      const bf16x8 pal = *(const bf16x8*)&pSL[po];
#pragma unroll
      for (int t = 0; t < 4; ++t) {
        const int vo = swzK(16 * t + l15, (kc * 4 + l4) * 8);
        const bf16x8 vbh = *(const bf16x8*)&VtH[vo];
        const bf16x8 vbl = *(const bf16x8*)&VtL[vo];
        acco[t] = MFMA(pah, vbh, acco[t]);
        acco[t] = MFMA(pah, vbl, acco[t]);
        acco[t] = MFMA(pal, vbh, acco[t]);
      }
    }
  }

  // epilogue
#pragma unroll
  for (int r = 0; r < 4; ++r) {
    const int q = q0 + 16 * w + l4 * 4 + r;
    const float inv = 1.f / lsum[r];
#pragma unroll
    for (int t = 0; t < 4; ++t)
      att[((size_t)b * SS + q) * EE + h * 64 + 16 * t + l15] = acco[t][r] * inv;
    if (l15 == 0)
      mln[((size_t)(b * HH + h)) * SS + q] = m[r] + __logf(lsum[r]);
  }
}

// ---------------------------------------------------------------------------
// k_avg: one block per (b, 64q x 64k); loops 16 heads, recomputes S via hi/lo
// MFMA, p = exp(s - mln), accumulates in C-layout regs, single write.
// ---------------------------------------------------------------------------
__global__ __launch_bounds__(256) void k_avg(
    const unsigned short* __restrict__ Qh, const unsigned short* __restrict__ Ql,
    const unsigned short* __restrict__ Kh, const unsigned short* __restrict__ Kl,
    const float* __restrict__ mln, float* __restrict__ avg)
{
  __shared__ __align__(16) unsigned short KsH[64 * 64], KsL[64 * 64];
  __shared__ float mlnS[16][64];

  const int tid  = threadIdx.x;
  const int lane = tid & 63;
  const int w    = tid >> 6;
  const int l15  = lane & 15;
  const int l4   = lane >> 4;
  const int k0   = blockIdx.x * 64;
  const int q0   = blockIdx.y * 64;
  const int b    = blockIdx.z;

  {  // stage mln for all 16 heads (read after the h=0 barriers)
    const int hh = tid >> 4, r4 = (tid & 15) * 4;
    *(float4*)&mlnS[hh][r4] =
        *(const float4*)&mln[((size_t)(b * HH + hh)) * SS + q0 + r4];
  }

  const int sr = tid >> 2;
  const int s1 = tid & 3;
  const int s2 = s1 + 4;
  const size_t kbase = (size_t)(b * SS + k0 + sr) * EE;
  const size_t qbase = (size_t)(b * SS + q0 + 16 * w + l15) * EE + l4 * 8;

  f32x4 av[4];
#pragma unroll
  for (int t = 0; t < 4; ++t) av[t] = zero4();

  // prefetch h = 0
  uint4 krh[2], krl[2];
  krh[0] = *(const uint4*)&Kh[kbase + s1 * 8]; krh[1] = *(const uint4*)&Kh[kbase + s2 * 8];
  krl[0] = *(const uint4*)&Kl[kbase + s1 * 8]; krl[1] = *(const uint4*)&Kl[kbase + s2 * 8];
  bf16x8 qh0 = *(const bf16x8*)&Qh[qbase];
  bf16x8 qh1 = *(const bf16x8*)&Qh[qbase + 32];
  bf16x8 ql0 = *(const bf16x8*)&Ql[qbase];
  bf16x8 ql1 = *(const bf16x8*)&Ql[qbase + 32];

  for (int h = 0; h < HH; ++h) {
    __syncthreads();
    *(uint4*)&KsH[swzK(sr, s1 * 8)] = krh[0];
    *(uint4*)&KsH[swzK(sr, s2 * 8)] = krh[1];
    *(uint4*)&KsL[swzK(sr, s1 * 8)] = krl[0];
    *(uint4*)&KsL[swzK(sr, s2 * 8)] = krl[1];
    __syncthreads();

    bf16x8 nqh0, nqh1, nql0, nql1;
    if (h + 1 < HH) {
      const size_t ko = kbase + (h + 1) * 64;
      krh[0] = *(const uint4*)&Kh[ko + s1 * 8]; krh[1] = *(const uint4*)&Kh[ko + s2 * 8];
      krl[0] = *(const uint4*)&Kl[ko + s1 * 8]; krl[1] = *(const uint4*)&Kl[ko + s2 * 8];
      const size_t qo = qbase + (h + 1) * 64;
      nqh0 = *(const bf16x8*)&Qh[qo];
      nqh1 = *(const bf16x8*)&Qh[qo + 32];
      nql0 = *(const bf16x8*)&Ql[qo];
      nql1 = *(const bf16x8*)&Ql[qo + 32];
    }

    f32x4 accs[4];
#pragma unroll
    for (int t = 0; t < 4; ++t) accs[t] = zero4();
#pragma unroll
    for (int t = 0; t < 4; ++t) {
      const int krow = 16 * t + l15;
#pragma unroll
      for (int c = 0; c < 2; ++c) {
        const int ko = swzK(krow, (c * 4 + l4) * 8);
        const bf16x8 bh = *(const bf16x8*)&KsH[ko];
        const bf16x8 bl = *(const bf16x8*)&KsL[ko];
        const bf16x8 qa = c ? qh1 : qh0;
        const bf16x8 qb = c ? ql1 : ql0;
        accs[t] = MFMA(qa, bh, accs[t]);
        accs[t] = MFMA(qa, bl, accs[t]);
        accs[t] = MFMA(qb, bh, accs[t]);
      }
    }

#pragma unroll
    for (int r = 0; r < 4; ++r) {
      const float mq = mlnS[h][16 * w + l4 * 4 + r];
#pragma unroll
      for (int t = 0; t < 4; ++t)
        av[t][r] += __expf(accs[t][r] - mq);
    }

    if (h + 1 < HH) { qh0 = nqh0; qh1 = nqh1; ql0 = nql0; ql1 = nql1; }
  }

  const float ih = 1.f / HH;
#pragma unroll
  for (int r = 0; r < 4; ++r) {
    const int q = q0 + 16 * w + l4 * 4 + r;
#pragma unroll
    for (int t = 0; t < 4; ++t)
      avg[((size_t)b * SS + q) * SS + k0 + 16 * t + l15] = av[t][r] * ih;
  }
}

// ---------------------------------------------------------------------------
extern "C" void kernel_launch(void* const* d_in, const int* in_sizes, int n_in,
                              void* d_out, int out_size, void* d_ws, size_t ws_size,
                              hipStream_t stream) {
  const float* q  = (const float*)d_in[0];
  const float* k  = (const float*)d_in[1];
  const float* v  = (const float*)d_in[2];
  const float* Wq = (const float*)d_in[3];
  const float* bq = (const float*)d_in[4];
  const float* Wk = (const float*)d_in[5];
  const float* bk = (const float*)d_in[6];
  const float* Wv = (const float*)d_in[7];
  const float* bv = (const float*)d_in[8];
  const float* Wo = (const float*)d_in[9];
  const float* bo = (const float*)d_in[10];

  // ws: 6 bf16 hi/lo arrays (6 x 8MB) + att fp32 (16MB) = 64MB
  unsigned short* wsu = (unsigned short*)d_ws;
  unsigned short* Qh = wsu;
  unsigned short* Ql = wsu + 1 * 4194304;
  unsigned short* Kh = wsu + 2 * 4194304;
  unsigned short* Kl = wsu + 3 * 4194304;
  unsigned short* Vh = wsu + 4 * 4194304;
  unsigned short* Vl = wsu + 5 * 4194304;
  float* att = (float*)(wsu + 6 * 4194304);

  float* outp = (float*)d_out;           // output [B,S,E]
  float* avg  = outp + 4194304;          // avg_attn [B,S,S]
  // mln[B,H,S] lives at the head of d_out; consumed by k_avg BEFORE k_gemm_o
  // overwrites that region (stream-ordered).
  float* mln  = outp;

  dim3 gqkv(EE / 128, NROW / 128, 3);    // (8,32,3)
  k_gemm_qkv<<<gqkv, 256, 0, stream>>>(q, k, v, Wq, Wk, Wv, bq, bk, bv,
                                       Qh, Ql, Kh, Kl, Vh, Vl);

  dim3 gfl(SS / 64, HH, BB);             // (32,16,2) = 1024 blocks
  k_flash<<<gfl, 256, 0, stream>>>(Qh, Ql, Kh, Kl, Vh, Vl, att, mln);

  dim3 gav(SS / 64, SS / 64, BB);        // (32,32,2) = 2048 blocks
  k_avg<<<gav, 256, 0, stream>>>(Qh, Ql, Kh, Kl, mln, avg);

  dim3 go(EE / 128, NROW / 128);         // (8,32)
  k_gemm_o<<<go, 256, 0, stream>>>(att, Wo, bo, outp);
}

// Round 10
// 746.908 us; speedup vs baseline: 4.4621x; 1.4288x over previous
//
#include <hip/hip_runtime.h>
#include <hip/hip_bf16.h>
#include <math.h>

#define BB 2
#define SS 2048
#define EE 1024
#define HH 16
#define DD 64
#define NROW (BB*SS)
#define SCALE 0.125f

typedef float f32x4 __attribute__((ext_vector_type(4)));
typedef __bf16 bf16x8 __attribute__((ext_vector_type(8)));

__device__ __forceinline__ f32x4 MFMA(bf16x8 a, bf16x8 b, f32x4 c){
  return __builtin_amdgcn_mfma_f32_16x16x32_bf16(a, b, c, 0, 0, 0);
}
__device__ __forceinline__ unsigned short f2bf(float x){   // RTN-even
  unsigned u = __builtin_bit_cast(unsigned, x);
  u = (u + 0x7FFFu + ((u >> 16) & 1u)) >> 16;
  return (unsigned short)u;
}
__device__ __forceinline__ float bf2f(unsigned short h){
  unsigned u = ((unsigned)h) << 16;
  return __builtin_bit_cast(float, u);
}
__device__ __forceinline__ f32x4 zero4(){
  f32x4 z; z[0]=0.f; z[1]=0.f; z[2]=0.f; z[3]=0.f; return z;
}
// split 8 fp32 -> 8 hi bf16 + 8 lo bf16 (packed uint4 each)
__device__ __forceinline__ void cvt8(float4 x0, float4 x1, uint4& hi, uint4& lo){
  unsigned short h[8], l[8];
  const float xs[8] = {x0.x, x0.y, x0.z, x0.w, x1.x, x1.y, x1.z, x1.w};
#pragma unroll
  for (int e = 0; e < 8; ++e) {
    unsigned short hh = f2bf(xs[e]);
    h[e] = hh;
    l[e] = f2bf(xs[e] - bf2f(hh));
  }
  hi = *(uint4*)h;
  lo = *(uint4*)l;
}

// LDS swizzles for [64][64] bf16 tiles (row stride 128B) — validated R8.
__device__ __forceinline__ int swzK(int row, int col){
  return row * 64 + (col ^ ((row & 7) << 3));
}
__device__ __forceinline__ int swzP(int row, int col){
  int slot = ((col >> 3) ^ (row & 7)) + 2 * ((row >> 2) & 3);
  return row * 64 + ((slot & 7) << 3) + (col & 7);
}
// LDS swizzle for [128][32] bf16 GEMM tiles (4 slots of 8): <=2-way everywhere
#define SWA(r, s) ((r) * 32 + ((((s) ^ ((r) & 3))) << 3))

// ---------------------------------------------------------------------------
// MFMA GEMM: out = X @ W.T + bias. hi/lo bf16 3-term (~fp32 accuracy).
// AMODE 0: A fp32 (convert in staging). AMODE 1: A pre-split (Ah,Al).
// OMODE 0: fp32 out. OMODE 1: hi/lo bf16 out, scaled.
// 128x128 tile, BK=32, 4 waves (2x2), 16 fragment-tiles/wave.
// ---------------------------------------------------------------------------
template<int AMODE, int OMODE>
__device__ __forceinline__ void gemm_mfma(
    const float* __restrict__ Xf,
    const unsigned short* __restrict__ Ah, const unsigned short* __restrict__ Al,
    const float* __restrict__ Wf, const float* __restrict__ bias,
    float* __restrict__ outf,
    unsigned short* __restrict__ oh, unsigned short* __restrict__ ol,
    float scale)
{
  __shared__ __align__(16) unsigned short sAH[128 * 32], sAL[128 * 32];
  __shared__ __align__(16) unsigned short sBH[128 * 32], sBL[128 * 32];

  const int tid  = threadIdx.x;
  const int lane = tid & 63;
  const int w    = tid >> 6;
  const int l15  = lane & 15;
  const int l4   = lane >> 4;
  const int wr   = w >> 1;
  const int wc   = w & 1;
  const int m0   = blockIdx.y * 128;
  const int n0   = blockIdx.x * 128;

  const int sr = tid >> 1;        // staging row 0..127
  const int sh = tid & 1;         // k-halves: offset sh*16, slots 2sh, 2sh+1

  f32x4 acc[4][4];
#pragma unroll
  for (int i = 0; i < 4; ++i)
#pragma unroll
    for (int j = 0; j < 4; ++j) acc[i][j] = zero4();

  float4 pa[4], pb[4];
  uint4  pau[4];
  // prefetch k-step 0
  if (AMODE == 0) {
    const float* ab = &Xf[(size_t)(m0 + sr) * EE + sh * 16];
    pa[0] = *(const float4*)&ab[0];  pa[1] = *(const float4*)&ab[4];
    pa[2] = *(const float4*)&ab[8];  pa[3] = *(const float4*)&ab[12];
  } else {
    const unsigned short* ahp = &Ah[(size_t)(m0 + sr) * EE + sh * 16];
    const unsigned short* alp = &Al[(size_t)(m0 + sr) * EE + sh * 16];
    pau[0] = *(const uint4*)&ahp[0]; pau[1] = *(const uint4*)&ahp[8];
    pau[2] = *(const uint4*)&alp[0]; pau[3] = *(const uint4*)&alp[8];
  }
  {
    const float* bb = &Wf[(size_t)(n0 + sr) * EE + sh * 16];
    pb[0] = *(const float4*)&bb[0];  pb[1] = *(const float4*)&bb[4];
    pb[2] = *(const float4*)&bb[8];  pb[3] = *(const float4*)&bb[12];
  }

  for (int kt = 0; kt < EE; kt += 32) {
    __syncthreads();
    {
      uint4 h0, l0;
      if (AMODE == 0) {
        cvt8(pa[0], pa[1], h0, l0);
        *(uint4*)&sAH[SWA(sr, 2 * sh)] = h0;
        *(uint4*)&sAL[SWA(sr, 2 * sh)] = l0;
        cvt8(pa[2], pa[3], h0, l0);
        *(uint4*)&sAH[SWA(sr, 2 * sh + 1)] = h0;
        *(uint4*)&sAL[SWA(sr, 2 * sh + 1)] = l0;
      } else {
        *(uint4*)&sAH[SWA(sr, 2 * sh)]     = pau[0];
        *(uint4*)&sAH[SWA(sr, 2 * sh + 1)] = pau[1];
        *(uint4*)&sAL[SWA(sr, 2 * sh)]     = pau[2];
        *(uint4*)&sAL[SWA(sr, 2 * sh + 1)] = pau[3];
      }
      cvt8(pb[0], pb[1], h0, l0);
      *(uint4*)&sBH[SWA(sr, 2 * sh)] = h0;
      *(uint4*)&sBL[SWA(sr, 2 * sh)] = l0;
      cvt8(pb[2], pb[3], h0, l0);
      *(uint4*)&sBH[SWA(sr, 2 * sh + 1)] = h0;
      *(uint4*)&sBL[SWA(sr, 2 * sh + 1)] = l0;
    }
    __syncthreads();

    // prefetch next k-step; latency hides under MFMA
    if (kt + 32 < EE) {
      if (AMODE == 0) {
        const float* ab = &Xf[(size_t)(m0 + sr) * EE + kt + 32 + sh * 16];
        pa[0] = *(const float4*)&ab[0];  pa[1] = *(const float4*)&ab[4];
        pa[2] = *(const float4*)&ab[8];  pa[3] = *(const float4*)&ab[12];
      } else {
        const unsigned short* ahp = &Ah[(size_t)(m0 + sr) * EE + kt + 32 + sh * 16];
        const unsigned short* alp = &Al[(size_t)(m0 + sr) * EE + kt + 32 + sh * 16];
        pau[0] = *(const uint4*)&ahp[0]; pau[1] = *(const uint4*)&ahp[8];
        pau[2] = *(const uint4*)&alp[0]; pau[3] = *(const uint4*)&alp[8];
      }
      const float* bb = &Wf[(size_t)(n0 + sr) * EE + kt + 32 + sh * 16];
      pb[0] = *(const float4*)&bb[0];  pb[1] = *(const float4*)&bb[4];
      pb[2] = *(const float4*)&bb[8];  pb[3] = *(const float4*)&bb[12];
    }

    bf16x8 ah[4], al[4], bh[4], bl[4];
#pragma unroll
    for (int i = 0; i < 4; ++i) {
      const int off = SWA(64 * wr + 16 * i + l15, l4);
      ah[i] = *(const bf16x8*)&sAH[off];
      al[i] = *(const bf16x8*)&sAL[off];
    }
#pragma unroll
    for (int j = 0; j < 4; ++j) {
      const int off = SWA(64 * wc + 16 * j + l15, l4);
      bh[j] = *(const bf16x8*)&sBH[off];
      bl[j] = *(const bf16x8*)&sBL[off];
    }
#pragma unroll
    for (int i = 0; i < 4; ++i)
#pragma unroll
      for (int j = 0; j < 4; ++j) {
        acc[i][j] = MFMA(ah[i], bh[j], acc[i][j]);
        acc[i][j] = MFMA(ah[i], bl[j], acc[i][j]);
        acc[i][j] = MFMA(al[i], bh[j], acc[i][j]);
      }
  }

  // epilogue: C/D layout col=l15, row=l4*4+r within each 16x16 tile
#pragma unroll
  for (int j = 0; j < 4; ++j) {
    const int col = n0 + 64 * wc + 16 * j + l15;
    const float bj = bias[col];
#pragma unroll
    for (int i = 0; i < 4; ++i) {
      const int rowb = m0 + 64 * wr + 16 * i + l4 * 4;
#pragma unroll
      for (int r = 0; r < 4; ++r) {
        const float v = acc[i][j][r] + bj;
        const size_t idx = (size_t)(rowb + r) * EE + col;
        if (OMODE == 0) {
          outf[idx] = v;
        } else {
          const float vs = v * scale;
          const unsigned short hi = f2bf(vs);
          oh[idx] = hi;
          ol[idx] = f2bf(vs - bf2f(hi));
        }
      }
    }
  }
}

__global__ __launch_bounds__(256) void k_gemm_qkv(
    const float* __restrict__ xq, const float* __restrict__ xk,
    const float* __restrict__ xv,
    const float* __restrict__ Wq, const float* __restrict__ Wk,
    const float* __restrict__ Wv,
    const float* __restrict__ bq, const float* __restrict__ bk,
    const float* __restrict__ bv,
    unsigned short* __restrict__ Qhp, unsigned short* __restrict__ Qlp,
    unsigned short* __restrict__ Khp, unsigned short* __restrict__ Klp,
    unsigned short* __restrict__ Vhp, unsigned short* __restrict__ Vlp)
{
  const int z = blockIdx.z;
  const float* X = (z == 0) ? xq : (z == 1) ? xk : xv;
  const float* W = (z == 0) ? Wq : (z == 1) ? Wk : Wv;
  const float* b = (z == 0) ? bq : (z == 1) ? bk : bv;
  unsigned short* oh = (z == 0) ? Qhp : (z == 1) ? Khp : Vhp;
  unsigned short* ol = (z == 0) ? Qlp : (z == 1) ? Klp : Vlp;
  const float scale = (z == 0) ? SCALE : 1.0f;   // fold Q scaling here
  gemm_mfma<0, 1>(X, nullptr, nullptr, W, b, nullptr, oh, ol, scale);
}

__global__ __launch_bounds__(256) void k_gemm_o(
    const unsigned short* __restrict__ atth, const unsigned short* __restrict__ attl,
    const float* __restrict__ Wo, const float* __restrict__ bo,
    float* __restrict__ out)
{
  gemm_mfma<1, 0>(nullptr, atth, attl, Wo, bo, out, nullptr, nullptr, 1.0f);
}

// ---------------------------------------------------------------------------
// k_flash: MFMA flash attention (validated R8). Epilogue now writes att as
// hi/lo bf16 so k_gemm_o consumes pre-split A.
// ---------------------------------------------------------------------------
__global__ __launch_bounds__(256) void k_flash(
    const unsigned short* __restrict__ Qh, const unsigned short* __restrict__ Ql,
    const unsigned short* __restrict__ Kh, const unsigned short* __restrict__ Kl,
    const unsigned short* __restrict__ Vh, const unsigned short* __restrict__ Vl,
    unsigned short* __restrict__ atth, unsigned short* __restrict__ attl,
    float* __restrict__ mln)
{
  __shared__ __align__(16) unsigned short KsH[64 * 64], KsL[64 * 64];
  __shared__ __align__(16) unsigned short VtH[64 * 64], VtL[64 * 64];
  __shared__ __align__(16) unsigned short pSH[64 * 64], pSL[64 * 64];

  const int tid  = threadIdx.x;
  const int lane = tid & 63;
  const int w    = tid >> 6;
  const int l15  = lane & 15;
  const int l4   = lane >> 4;
  const int q0   = blockIdx.x * 64;
  const int h    = blockIdx.y;
  const int b    = blockIdx.z;

  const size_t hb = (size_t)b * SS * EE + h * 64;

  const size_t qoff = hb + (size_t)(q0 + 16 * w + l15) * EE + l4 * 8;
  const bf16x8 qh0 = *(const bf16x8*)&Qh[qoff];
  const bf16x8 qh1 = *(const bf16x8*)&Qh[qoff + 32];
  const bf16x8 ql0 = *(const bf16x8*)&Ql[qoff];
  const bf16x8 ql1 = *(const bf16x8*)&Ql[qoff + 32];

  const int sr = tid >> 2;
  const int s1 = tid & 3;
  const int s2 = s1 + 4;

  uint4 krh[2], krl[2], vrh[2], vrl[2];
  {
    const size_t ko = hb + (size_t)sr * EE;
    krh[0] = *(const uint4*)&Kh[ko + s1 * 8]; krh[1] = *(const uint4*)&Kh[ko + s2 * 8];
    krl[0] = *(const uint4*)&Kl[ko + s1 * 8]; krl[1] = *(const uint4*)&Kl[ko + s2 * 8];
    vrh[0] = *(const uint4*)&Vh[ko + s1 * 8]; vrh[1] = *(const uint4*)&Vh[ko + s2 * 8];
    vrl[0] = *(const uint4*)&Vl[ko + s1 * 8]; vrl[1] = *(const uint4*)&Vl[ko + s2 * 8];
  }

  float m[4]    = {-1e30f, -1e30f, -1e30f, -1e30f};
  float lsum[4] = {0.f, 0.f, 0.f, 0.f};
  f32x4 acco[4];
#pragma unroll
  for (int t = 0; t < 4; ++t) acco[t] = zero4();

  for (int kt = 0; kt < SS; kt += 64) {
    __syncthreads();
    {
      *(uint4*)&KsH[swzK(sr, s1 * 8)] = krh[0];
      *(uint4*)&KsH[swzK(sr, s2 * 8)] = krh[1];
      *(uint4*)&KsL[swzK(sr, s1 * 8)] = krl[0];
      *(uint4*)&KsL[swzK(sr, s2 * 8)] = krl[1];
#pragma unroll
      for (int u = 0; u < 2; ++u) {
        const int d0 = (u ? s2 : s1) * 8;
        const unsigned short* pv = (const unsigned short*)&vrh[u];
        const unsigned short* pw = (const unsigned short*)&vrl[u];
#pragma unroll
        for (int e = 0; e < 8; ++e) {
          const int idx = swzK(d0 + e, sr);
          VtH[idx] = pv[e];
          VtL[idx] = pw[e];
        }
      }
    }
    __syncthreads();

    if (kt + 64 < SS) {
      const size_t ko = hb + (size_t)(kt + 64 + sr) * EE;
      krh[0] = *(const uint4*)&Kh[ko + s1 * 8]; krh[1] = *(const uint4*)&Kh[ko + s2 * 8];
      krl[0] = *(const uint4*)&Kl[ko + s1 * 8]; krl[1] = *(const uint4*)&Kl[ko + s2 * 8];
      vrh[0] = *(const uint4*)&Vh[ko + s1 * 8]; vrh[1] = *(const uint4*)&Vh[ko + s2 * 8];
      vrl[0] = *(const uint4*)&Vl[ko + s1 * 8]; vrl[1] = *(const uint4*)&Vl[ko + s2 * 8];
    }

    f32x4 accs[4];
#pragma unroll
    for (int t = 0; t < 4; ++t) accs[t] = zero4();
#pragma unroll
    for (int t = 0; t < 4; ++t) {
      const int krow = 16 * t + l15;
#pragma unroll
      for (int c = 0; c < 2; ++c) {
        const int ko = swzK(krow, (c * 4 + l4) * 8);
        const bf16x8 bh = *(const bf16x8*)&KsH[ko];
        const bf16x8 bl = *(const bf16x8*)&KsL[ko];
        const bf16x8 qa = c ? qh1 : qh0;
        const bf16x8 qb = c ? ql1 : ql0;
        accs[t] = MFMA(qa, bh, accs[t]);
        accs[t] = MFMA(qa, bl, accs[t]);
        accs[t] = MFMA(qb, bh, accs[t]);
      }
    }

    const int prow_base = 16 * w + l4 * 4;
#pragma unroll
    for (int r = 0; r < 4; ++r) {
      float tmax = fmaxf(fmaxf(accs[0][r], accs[1][r]),
                         fmaxf(accs[2][r], accs[3][r]));
#pragma unroll
      for (int off = 8; off >= 1; off >>= 1)
        tmax = fmaxf(tmax, __shfl_xor(tmax, off));
      const float mn = fmaxf(m[r], tmax);
      const float sc = __expf(m[r] - mn);
      float pv[4];
      float ts = 0.f;
#pragma unroll
      for (int t = 0; t < 4; ++t) { pv[t] = __expf(accs[t][r] - mn); ts += pv[t]; }
#pragma unroll
      for (int off = 8; off >= 1; off >>= 1)
        ts += __shfl_xor(ts, off);
      lsum[r] = lsum[r] * sc + ts;
      m[r] = mn;
      const int prow = prow_base + r;
#pragma unroll
      for (int t = 0; t < 4; ++t) {
        const unsigned short hi = f2bf(pv[t]);
        const unsigned short lo = f2bf(pv[t] - bf2f(hi));
        const int idx = swzP(prow, 16 * t + l15);
        pSH[idx] = hi;
        pSL[idx] = lo;
      }
#pragma unroll
      for (int t = 0; t < 4; ++t) acco[t][r] *= sc;
    }

    const int parow = 16 * w + l15;
#pragma unroll
    for (int kc = 0; kc < 2; ++kc) {
      const int po = swzP(parow, kc * 32 + l4 * 8);
      const bf16x8 pah = *(const bf16x8*)&pSH[po];
      const bf16x8 pal = *(const bf16x8*)&pSL[po];
#pragma unroll
      for (int t = 0; t < 4; ++t) {
        const int vo = swzK(16 * t + l15, (kc * 4 + l4) * 8);
        const bf16x8 vbh = *(const bf16x8*)&VtH[vo];
        const bf16x8 vbl = *(const bf16x8*)&VtL[vo];
        acco[t] = MFMA(pah, vbh, acco[t]);
        acco[t] = MFMA(pah, vbl, acco[t]);
        acco[t] = MFMA(pal, vbh, acco[t]);
      }
    }
  }

  // epilogue: att as hi/lo bf16
#pragma unroll
  for (int r = 0; r < 4; ++r) {
    const int q = q0 + 16 * w + l4 * 4 + r;
    const float inv = 1.f / lsum[r];
#pragma unroll
    for (int t = 0; t < 4; ++t) {
      const float v = acco[t][r] * inv;
      const size_t idx = ((size_t)b * SS + q) * EE + h * 64 + 16 * t + l15;
      const unsigned short hi = f2bf(v);
      atth[idx] = hi;
      attl[idx] = f2bf(v - bf2f(hi));
    }
    if (l15 == 0)
      mln[((size_t)(b * HH + h)) * SS + q] = m[r] + __logf(lsum[r]);
  }
}

// ---------------------------------------------------------------------------
// k_avg: unchanged from R8 (validated).
// ---------------------------------------------------------------------------
__global__ __launch_bounds__(256) void k_avg(
    const unsigned short* __restrict__ Qh, const unsigned short* __restrict__ Ql,
    const unsigned short* __restrict__ Kh, const unsigned short* __restrict__ Kl,
    const float* __restrict__ mln, float* __restrict__ avg)
{
  __shared__ __align__(16) unsigned short KsH[64 * 64], KsL[64 * 64];
  __shared__ float mlnS[16][64];

  const int tid  = threadIdx.x;
  const int lane = tid & 63;
  const int w    = tid >> 6;
  const int l15  = lane & 15;
  const int l4   = lane >> 4;
  const int k0   = blockIdx.x * 64;
  const int q0   = blockIdx.y * 64;
  const int b    = blockIdx.z;

  {
    const int hh = tid >> 4, r4 = (tid & 15) * 4;
    *(float4*)&mlnS[hh][r4] =
        *(const float4*)&mln[((size_t)(b * HH + hh)) * SS + q0 + r4];
  }

  const int sr = tid >> 2;
  const int s1 = tid & 3;
  const int s2 = s1 + 4;
  const size_t kbase = (size_t)(b * SS + k0 + sr) * EE;
  const size_t qbase = (size_t)(b * SS + q0 + 16 * w + l15) * EE + l4 * 8;

  f32x4 av[4];
#pragma unroll
  for (int t = 0; t < 4; ++t) av[t] = zero4();

  uint4 krh[2], krl[2];
  krh[0] = *(const uint4*)&Kh[kbase + s1 * 8]; krh[1] = *(const uint4*)&Kh[kbase + s2 * 8];
  krl[0] = *(const uint4*)&Kl[kbase + s1 * 8]; krl[1] = *(const uint4*)&Kl[kbase + s2 * 8];
  bf16x8 qh0 = *(const bf16x8*)&Qh[qbase];
  bf16x8 qh1 = *(const bf16x8*)&Qh[qbase + 32];
  bf16x8 ql0 = *(const bf16x8*)&Ql[qbase];
  bf16x8 ql1 = *(const bf16x8*)&Ql[qbase + 32];

  for (int h = 0; h < HH; ++h) {
    __syncthreads();
    *(uint4*)&KsH[swzK(sr, s1 * 8)] = krh[0];
    *(uint4*)&KsH[swzK(sr, s2 * 8)] = krh[1];
    *(uint4*)&KsL[swzK(sr, s1 * 8)] = krl[0];
    *(uint4*)&KsL[swzK(sr, s2 * 8)] = krl[1];
    __syncthreads();

    bf16x8 nqh0, nqh1, nql0, nql1;
    if (h + 1 < HH) {
      const size_t ko = kbase + (h + 1) * 64;
      krh[0] = *(const uint4*)&Kh[ko + s1 * 8]; krh[1] = *(const uint4*)&Kh[ko + s2 * 8];
      krl[0] = *(const uint4*)&Kl[ko + s1 * 8]; krl[1] = *(const uint4*)&Kl[ko + s2 * 8];
      const size_t qo = qbase + (h + 1) * 64;
      nqh0 = *(const bf16x8*)&Qh[qo];
      nqh1 = *(const bf16x8*)&Qh[qo + 32];
      nql0 = *(const bf16x8*)&Ql[qo];
      nql1 = *(const bf16x8*)&Ql[qo + 32];
    }

    f32x4 accs[4];
#pragma unroll
    for (int t = 0; t < 4; ++t) accs[t] = zero4();
#pragma unroll
    for (int t = 0; t < 4; ++t) {
      const int krow = 16 * t + l15;
#pragma unroll
      for (int c = 0; c < 2; ++c) {
        const int ko = swzK(krow, (c * 4 + l4) * 8);
        const bf16x8 bh = *(const bf16x8*)&KsH[ko];
        const bf16x8 bl = *(const bf16x8*)&KsL[ko];
        const bf16x8 qa = c ? qh1 : qh0;
        const bf16x8 qb = c ? ql1 : ql0;
        accs[t] = MFMA(qa, bh, accs[t]);
        accs[t] = MFMA(qa, bl, accs[t]);
        accs[t] = MFMA(qb, bh, accs[t]);
      }
    }

#pragma unroll
    for (int r = 0; r < 4; ++r) {
      const float mq = mlnS[h][16 * w + l4 * 4 + r];
#pragma unroll
      for (int t = 0; t < 4; ++t)
        av[t][r] += __expf(accs[t][r] - mq);
    }

    if (h + 1 < HH) { qh0 = nqh0; qh1 = nqh1; ql0 = nql0; ql1 = nql1; }
  }

  const float ih = 1.f / HH;
#pragma unroll
  for (int r = 0; r < 4; ++r) {
    const int q = q0 + 16 * w + l4 * 4 + r;
#pragma unroll
    for (int t = 0; t < 4; ++t)
      avg[((size_t)b * SS + q) * SS + k0 + 16 * t + l15] = av[t][r] * ih;
  }
}

// ---------------------------------------------------------------------------
extern "C" void kernel_launch(void* const* d_in, const int* in_sizes, int n_in,
                              void* d_out, int out_size, void* d_ws, size_t ws_size,
                              hipStream_t stream) {
  const float* q  = (const float*)d_in[0];
  const float* k  = (const float*)d_in[1];
  const float* v  = (const float*)d_in[2];
  const float* Wq = (const float*)d_in[3];
  const float* bq = (const float*)d_in[4];
  const float* Wk = (const float*)d_in[5];
  const float* bk = (const float*)d_in[6];
  const float* Wv = (const float*)d_in[7];
  const float* bv = (const float*)d_in[8];
  const float* Wo = (const float*)d_in[9];
  const float* bo = (const float*)d_in[10];

  // ws: 8 bf16 arrays x 8MB = 64MB (same footprint as validated R8 layout)
  unsigned short* wsu = (unsigned short*)d_ws;
  unsigned short* Qh   = wsu;
  unsigned short* Ql   = wsu + 1 * 4194304;
  unsigned short* Kh   = wsu + 2 * 4194304;
  unsigned short* Kl   = wsu + 3 * 4194304;
  unsigned short* Vh   = wsu + 4 * 4194304;
  unsigned short* Vl   = wsu + 5 * 4194304;
  unsigned short* atth = wsu + 6 * 4194304;
  unsigned short* attl = wsu + 7 * 4194304;

  float* outp = (float*)d_out;           // output [B,S,E]
  float* avg  = outp + 4194304;          // avg_attn [B,S,S]
  float* mln  = outp;                    // consumed by k_avg before k_gemm_o

  dim3 gqkv(EE / 128, NROW / 128, 3);    // (8,32,3)
  k_gemm_qkv<<<gqkv, 256, 0, stream>>>(q, k, v, Wq, Wk, Wv, bq, bk, bv,
                                       Qh, Ql, Kh, Kl, Vh, Vl);

  dim3 gfl(SS / 64, HH, BB);             // (32,16,2) = 1024 blocks
  k_flash<<<gfl, 256, 0, stream>>>(Qh, Ql, Kh, Kl, Vh, Vl, atth, attl, mln);

  dim3 gav(SS / 64, SS / 64, BB);        // (32,32,2) = 2048 blocks
  k_avg<<<gav, 256, 0, stream>>>(Qh, Ql, Kh, Kl, mln, avg);

  dim3 go(EE / 128, NROW / 128);         // (8,32)
  k_gemm_o<<<go, 256, 0, stream>>>(atth, attl, Wo, bo, outp);
}